// Round 13
// baseline (573.245 us; speedup 1.0000x reference)
//
#include <hip/hip_runtime.h>
#include <hip/hip_fp16.h>
#include <math.h>

// GAT encoder: N=10000, E=160000 (+N self loops), H=8 heads, C=128, D=1024.
// Best: 241.1us (R25 ring + swizzled weights); R28 nt-hints neutral.
// Tail cost (~35us/dispatch) still unexplained after 3 nulls + 2 failed
// models. R29: MEASUREMENT ROUND. Pipeline = R28 unchanged; 4 probes on
// layer-3 inputs (x5 reps, scratch out), each with UNIQUE LDS fingerprint:
//   ptail<1> stage1 full | <2> stage2 only | <3> stage1 no-gelu |
//   <4> stage1 no-weight-loads (synthetic A).
// Readout: V3<<V1 => erff is the sink; V4<<V1 => weight-load latency;
// V1~V3~V4 => irreducible, plateau at ~241.

#define THREADS 256
#define CAP 128

typedef _Float16 f16x8 __attribute__((ext_vector_type(8)));
typedef float f32x4 __attribute__((ext_vector_type(4)));
typedef float f32x2 __attribute__((ext_vector_type(2)));

struct __align__(8) Half4 { __half2 a, b; };

__device__ __forceinline__ float gelu_exact(float x) {
  return 0.5f * x * (1.0f + erff(x * 0.70710678118654752f));
}

__device__ __forceinline__ void nt_store8(void* dst, const Half4& v) {
  __builtin_nontemporal_store(*(const unsigned long long*)&v,
                              (unsigned long long*)dst);
}

// ---------------- fused prep: hist + weight swizzle/convert + score-vectors ----------------

__global__ __launch_bounds__(256) void prep_kernel(
    const int* __restrict__ ei, int E, int ET, int* __restrict__ counts,
    const float* __restrict__ w2, const float* __restrict__ w3,
    const float* __restrict__ rw1, const float* __restrict__ rw2,
    const float* __restrict__ lw,
    __half* __restrict__ wt2, __half* __restrict__ wt3,
    __half* __restrict__ rwt1, __half* __restrict__ rwt2,
    __half* __restrict__ lwt,
    const float* __restrict__ w1,
    const float* __restrict__ as1, const float* __restrict__ ad1,
    const float* __restrict__ as2, const float* __restrict__ ad2,
    const float* __restrict__ as3, const float* __restrict__ ad3,
    float* __restrict__ ws1, float* __restrict__ wd1,
    float* __restrict__ ws2, float* __restrict__ wd2,
    float* __restrict__ ws3, float* __restrict__ wd3,
    int nHist) {
  __shared__ float tile[32][33];
  int bid = blockIdx.x;
  int t = threadIdx.x;

  if (bid < nHist) {
    int e = bid * 256 + t;
    if (e >= ET) return;
    int d = (e < E) ? ei[E + e] : (e - E);
    atomicAdd(&counts[d], 1);
    return;
  }
  bid -= nHist;
  if (bid < 640) {
    const float* in; __half* out; int K, Ncol;
    int z = bid >> 7, rem = bid & 127;
    switch (z) {
      case 0: in = w2;  out = wt2;  K = 128;  Ncol = 1024; break;
      case 1: in = w3;  out = wt3;  K = 128;  Ncol = 1024; break;
      case 2: in = rw1; out = rwt1; K = 1024; Ncol = 128;  break;
      case 3: in = rw2; out = rwt2; K = 1024; Ncol = 128;  break;
      default: in = lw; out = lwt;  K = 1024; Ncol = 128;  break;
    }
    int kt2, ct2;
    if (z < 2) { kt2 = rem >> 5; ct2 = rem & 31; }
    else       { kt2 = rem & 31; ct2 = rem >> 5; }
    int kb = kt2 * 32, cb = ct2 * 32;
    int KT = K >> 5;
    int tc = t & 31, tr = t >> 5;
#pragma unroll
    for (int r = tr; r < 32; r += 8)
      tile[r][tc] = in[(size_t)(kb + r) * Ncol + cb + tc];
    __syncthreads();
#pragma unroll
    for (int r = tr; r < 32; r += 8) {
      int c = cb + r, k = kb + tc;
      int m = c & 15, ct = c >> 4;
      int j = k & 7, quad = (k >> 3) & 3, kt = k >> 5;
      out[((size_t)(ct * KT + kt) * 64 + quad * 16 + m) * 8 + j] =
          __float2half_rn(tile[tc][r]);
    }
    return;
  }
  bid -= 640;
  {
    int h = bid & 7, yy = bid >> 3;
    int sel = t >> 7;
    int k = t & 127;
    const float* W; const float* av; float* outp; int K;
    switch (yy) {
      case 0: W = w2; av = sel ? ad2 : as2; outp = sel ? wd2 : ws2; K = 128; break;
      case 1: W = w3; av = sel ? ad3 : as3; outp = sel ? wd3 : ws3; K = 128; break;
      default: W = w1; av = sel ? ad1 : as1; outp = sel ? wd1 : ws1; K = 4; break;
    }
    if (k >= K) return;
    const float* wrow = W + (size_t)k * 1024 + h * 128;
    const float* arow = av + h * 128;
    float s = 0.f;
    for (int c = 0; c < 128; c += 4) {
      float4 wv = *(const float4*)&wrow[c];
      float4 a4 = *(const float4*)&arow[c];
      s += wv.x * a4.x + wv.y * a4.y + wv.z * a4.z + wv.w * a4.w;
    }
    outp[h * K + k] = s;
  }
}

// ---------------- scan (block 0) || layer-1 scores (blocks 1..) ----------------

__global__ __launch_bounds__(1024) void scan_scores_kernel(
    const int* __restrict__ counts, int* __restrict__ offsets,
    int* __restrict__ cursor, int n,
    const float* __restrict__ x,
    const float* __restrict__ ws1, const float* __restrict__ wd1,
    float* __restrict__ ssrc, float* __restrict__ sdst, int total) {
  __shared__ int sums[1024];
  if (blockIdx.x == 0) {
    int t = threadIdx.x;
    int per = (n + 1023) >> 10;
    int start = t * per; if (start > n) start = n;
    int end = start + per; if (end > n) end = n;
    int local = 0;
    for (int i = start; i < end; ++i) local += counts[i];
    sums[t] = local;
    __syncthreads();
    for (int off = 1; off < 1024; off <<= 1) {
      int add = (t >= off) ? sums[t - off] : 0;
      __syncthreads();
      sums[t] += add;
      __syncthreads();
    }
    int run = (t == 0) ? 0 : sums[t - 1];
    for (int i = start; i < end; ++i) {
      offsets[i] = run; cursor[i] = run; run += counts[i];
    }
    if (t == 1023) offsets[n] = run;
    return;
  }
  int idx = (blockIdx.x - 1) * 1024 + threadIdx.x;
  if (idx >= total) return;
  int nn = idx >> 3, h = idx & 7;
  float4 xv = *(const float4*)&x[nn * 4];
  float4 a = *(const float4*)&ws1[h * 4];
  float4 b = *(const float4*)&wd1[h * 4];
  ssrc[idx] = xv.x * a.x + xv.y * a.y + xv.z * a.z + xv.w * a.w;
  sdst[idx] = xv.x * b.x + xv.y * b.y + xv.z * b.z + xv.w * b.w;
}

__global__ void scatter_kernel(const int* __restrict__ ei, int E, int ET,
                               int* __restrict__ cursor, int* __restrict__ srcs) {
  int e = blockIdx.x * THREADS + threadIdx.x;
  if (e >= ET) return;
  int s = (e < E) ? ei[e] : (e - E);
  int d = (e < E) ? ei[E + e] : (e - E);
  int pos = atomicAdd(&cursor[d], 1);
  srcs[pos] = s;
}

// ---------------- fused attention + aggregation (P16), wave per node ----------------

__global__ __launch_bounds__(256) void attnagg_p(const __half* __restrict__ P16,
                                                 const int* __restrict__ srcs,
                                                 const int* __restrict__ offsets,
                                                 const float* __restrict__ ssrc,
                                                 const float* __restrict__ sdst,
                                                 __half* __restrict__ Y16, int NP) {
  __shared__ float lal[4][CAP][8];
  __shared__ int ls[4][CAP];
  __shared__ float szinv[4][8];
  int w = threadIdx.x >> 6, lane = threadIdx.x & 63;
  int n = blockIdx.x * 4 + w;
  int start = offsets[n], deg = offsets[n + 1] - start;
  int head = lane & 7, es = lane >> 3;
  float sd = sdst[n * 8 + head];
  int c2 = lane * 2;
  const __half* pbase = P16 + c2;
  f32x2 acc2[8] = {};
  float s = 0.f;
  for (int cc = 0; cc < deg; cc += CAP) {
    int cm = min(CAP, deg - cc);
    for (int i = es; i < cm; i += 8) {
      int sp = srcs[start + cc + i];
      float v = ssrc[sp * 8 + head] + sd;
      v = (v > 0.f) ? v : 0.2f * v;
      float e = __expf(v);
      lal[w][i][head] = e;
      if (head == 0) ls[w][i] = sp;
      s += e;
    }
    int i = 0;
    for (; i + 8 <= cm; i += 8) {
      f32x2 pp[8];
#pragma unroll
      for (int u = 0; u < 8; ++u) {
        int sp = ls[w][i + u];
        float2 f = __half22float2(*(const __half2*)&pbase[(size_t)sp * 128]);
        pp[u].x = f.x; pp[u].y = f.y;
      }
#pragma unroll
      for (int u = 0; u < 8; ++u) {
        float4 a00 = *(float4*)&lal[w][i + u][0];
        float4 a01 = *(float4*)&lal[w][i + u][4];
        float a0[8] = {a00.x, a00.y, a00.z, a00.w, a01.x, a01.y, a01.z, a01.w};
#pragma unroll
        for (int h = 0; h < 8; ++h) acc2[h] += a0[h] * pp[u];
      }
    }
    for (; i < cm; ++i) {
      int sp0 = ls[w][i];
      float2 f = __half22float2(*(const __half2*)&pbase[(size_t)sp0 * 128]);
      f32x2 p0; p0.x = f.x; p0.y = f.y;
      float4 a00 = *(float4*)&lal[w][i][0];
      float4 a01 = *(float4*)&lal[w][i][4];
      float a0[8] = {a00.x, a00.y, a00.z, a00.w, a01.x, a01.y, a01.z, a01.w};
#pragma unroll
      for (int h = 0; h < 8; ++h) acc2[h] += a0[h] * p0;
    }
  }
#pragma unroll
  for (int mask = 8; mask <= 32; mask <<= 1)
    s += __shfl_xor(s, mask);
  if (es == 0) szinv[w][head] = 1.f / s;
#pragma unroll
  for (int h = 0; h < 8; ++h) {
    float zi = szinv[w][h];
    __half2 hv = __floats2half2_rn(acc2[h].x * zi, acc2[h].y * zi);
    __builtin_nontemporal_store(*(const unsigned int*)&hv,
        (unsigned int*)&Y16[((size_t)h * NP + n) * 128 + c2]);
  }
}

// ---------------- fused attention + aggregation (layer 1, raw x) ----------------

__global__ __launch_bounds__(256) void attnagg_x(const float* __restrict__ x,
                                                 const int* __restrict__ srcs,
                                                 const int* __restrict__ offsets,
                                                 const float* __restrict__ ssrc,
                                                 const float* __restrict__ sdst,
                                                 float* __restrict__ Y1, int NP) {
  __shared__ float lal[4][CAP][8];
  __shared__ int ls[4][CAP];
  __shared__ float szinv[4][8];
  int w = threadIdx.x >> 6, lane = threadIdx.x & 63;
  int n = blockIdx.x * 4 + w;
  int start = offsets[n], deg = offsets[n + 1] - start;
  int head = lane & 7, es = lane >> 3;
  float sd = sdst[n * 8 + head];
  int eo = lane >> 5, hb = (lane >> 2) & 7, ch = lane & 3;
  float acc = 0.f;
  float s = 0.f;
  for (int cc = 0; cc < deg; cc += CAP) {
    int cm = min(CAP, deg - cc);
    for (int i = es; i < cm; i += 8) {
      int sp = srcs[start + cc + i];
      float v = ssrc[sp * 8 + head] + sd;
      v = (v > 0.f) ? v : 0.2f * v;
      float e = __expf(v);
      lal[w][i][head] = e;
      if (head == 0) ls[w][i] = sp;
      s += e;
    }
    int i = eo;
    for (; i + 6 < cm; i += 8) {
      float xv[4]; float av[4];
#pragma unroll
      for (int u = 0; u < 4; ++u) {
        int sp = ls[w][i + 2 * u];
        xv[u] = x[sp * 4 + ch];
      }
#pragma unroll
      for (int u = 0; u < 4; ++u) av[u] = lal[w][i + 2 * u][hb];
#pragma unroll
      for (int u = 0; u < 4; ++u) acc += av[u] * xv[u];
    }
    for (; i < cm; i += 2) {
      int sp = ls[w][i];
      acc += lal[w][i][hb] * x[sp * 4 + ch];
    }
  }
#pragma unroll
  for (int mask = 8; mask <= 32; mask <<= 1)
    s += __shfl_xor(s, mask);
  if (es == 0) szinv[w][head] = 1.f / s;
  acc += __shfl_xor(acc, 32);
  if (lane < 32) {
    float zi = szinv[w][hb];
    Y1[((size_t)hb * NP + n) * 4 + ch] = acc * zi;
  }
}

// ---------------- fused tail (layers 2/3): 32 rows, VGPR<=128, 16-slot ring, nt ----------------

template <typename OutT, bool SC>
__global__ __launch_bounds__(512, 4) void tail_mfma(const __half* __restrict__ Y16,
                                                    const __half* __restrict__ WtA,
                                                    const float* __restrict__ biasA,
                                                    const __half* __restrict__ WtP,
                                                    const float* __restrict__ biasP,
                                                    OutT* __restrict__ out, int N, int NP,
                                                    const float* __restrict__ wsn,
                                                    const float* __restrict__ wdn,
                                                    float* __restrict__ ssrc,
                                                    float* __restrict__ sdst) {
  __shared__ __half Gt[32][1032];
  __shared__ __half Pl[32][136];
  int w = threadIdx.x >> 6, lane = threadIdx.x & 63;
  int r0 = blockIdx.x * 32;
  int m = lane & 15, quad = lane >> 4;
  // stage 1
  {
    int h = w;
    const __half* py0 = Y16 + ((size_t)h * NP + r0 + m) * 128 + quad * 8;
    const __half* py1 = py0 + (size_t)16 * 128;
    f16x8 bf0[4], bf1[4];
#pragma unroll
    for (int kk = 0; kk < 4; ++kk) {
      bf0[kk] = __builtin_nontemporal_load((const f16x8*)(py0 + kk * 32));
      bf1[kk] = __builtin_nontemporal_load((const f16x8*)(py1 + kk * 32));
    }
    const __half* wbase = WtA + (size_t)h * 8 * 2048 + lane * 8;
    f16x8 aA[4], aB[4];
#pragma unroll
    for (int kk = 0; kk < 4; ++kk) aA[kk] = *(const f16x8*)(wbase + kk * 512);
#pragma unroll
    for (int tile = 0; tile < 8; ++tile) {
      if (tile < 7) {
        const __half* pn = wbase + (size_t)(tile + 1) * 2048;
        if ((tile & 1) == 0) {
#pragma unroll
          for (int kk = 0; kk < 4; ++kk) aB[kk] = *(const f16x8*)(pn + kk * 512);
        } else {
#pragma unroll
          for (int kk = 0; kk < 4; ++kk) aA[kk] = *(const f16x8*)(pn + kk * 512);
        }
      }
      int gc = w * 128 + tile * 16;
      f32x4 acc0 = {0.f, 0.f, 0.f, 0.f}, acc1 = {0.f, 0.f, 0.f, 0.f};
#pragma unroll
      for (int kk = 0; kk < 4; ++kk) {
        f16x8 av = ((tile & 1) == 0) ? aA[kk] : aB[kk];
        acc0 = __builtin_amdgcn_mfma_f32_16x16x32_f16(av, bf0[kk], acc0, 0, 0, 0);
        acc1 = __builtin_amdgcn_mfma_f32_16x16x32_f16(av, bf1[kk], acc1, 0, 0, 0);
      }
      float4 b4 = *(const float4*)&biasA[gc + quad * 4];
      Half4 p0, p1;
      p0.a = __floats2half2_rn(gelu_exact(acc0[0] + b4.x), gelu_exact(acc0[1] + b4.y));
      p0.b = __floats2half2_rn(gelu_exact(acc0[2] + b4.z), gelu_exact(acc0[3] + b4.w));
      p1.a = __floats2half2_rn(gelu_exact(acc1[0] + b4.x), gelu_exact(acc1[1] + b4.y));
      p1.b = __floats2half2_rn(gelu_exact(acc1[2] + b4.z), gelu_exact(acc1[3] + b4.w));
      *(Half4*)&Gt[m][gc + quad * 4] = p0;
      *(Half4*)&Gt[16 + m][gc + quad * 4] = p1;
    }
  }
  __syncthreads();
  // stage 2
  {
    int c0 = w * 16;
    const __half* pa = WtP + (size_t)w * 16384 + lane * 8;
    f16x8 ring[16];
#pragma unroll
    for (int u = 0; u < 16; ++u) ring[u] = *(const f16x8*)(pa + u * 512);
    f32x4 acc0 = {0.f, 0.f, 0.f, 0.f}, acc1 = {0.f, 0.f, 0.f, 0.f};
#pragma unroll
    for (int u = 0; u < 32; ++u) {
      int k = u * 32;
      f16x8 av = ring[u & 15];
      f16x8 b0 = *(const f16x8*)&Gt[m][quad * 8 + k];
      f16x8 b1 = *(const f16x8*)&Gt[16 + m][quad * 8 + k];
      acc0 = __builtin_amdgcn_mfma_f32_16x16x32_f16(av, b0, acc0, 0, 0, 0);
      acc1 = __builtin_amdgcn_mfma_f32_16x16x32_f16(av, b1, acc1, 0, 0, 0);
      if (u < 16) ring[u & 15] = *(const f16x8*)(pa + (u + 16) * 512);
    }
    float4 b4 = *(const float4*)&biasP[c0 + quad * 4];
    int row0 = r0 + m, row1 = r0 + 16 + m;
    if constexpr (__is_same(OutT, __half)) {
      Half4 p, q;
      p.a = __floats2half2_rn(acc0[0] + b4.x, acc0[1] + b4.y);
      p.b = __floats2half2_rn(acc0[2] + b4.z, acc0[3] + b4.w);
      q.a = __floats2half2_rn(acc1[0] + b4.x, acc1[1] + b4.y);
      q.b = __floats2half2_rn(acc1[2] + b4.z, acc1[3] + b4.w);
      if constexpr (SC) {
        *(Half4*)&Pl[m][c0 + quad * 4] = p;
        *(Half4*)&Pl[16 + m][c0 + quad * 4] = q;
      }
      if (row0 < N) nt_store8(&out[(size_t)row0 * 128 + c0 + quad * 4], p);
      if (row1 < N) nt_store8(&out[(size_t)row1 * 128 + c0 + quad * 4], q);
    } else {
      if (row0 < N)
        *(float4*)&out[(size_t)row0 * 128 + c0 + quad * 4] =
            make_float4(acc0[0] + b4.x, acc0[1] + b4.y, acc0[2] + b4.z, acc0[3] + b4.w);
      if (row1 < N)
        *(float4*)&out[(size_t)row1 * 128 + c0 + quad * 4] =
            make_float4(acc1[0] + b4.x, acc1[1] + b4.y, acc1[2] + b4.z, acc1[3] + b4.w);
    }
  }
  if constexpr (SC) {
    __syncthreads();
    int head = lane & 7, es = lane >> 3;
    const float* wsp = wsn + head * 128 + es * 16;
    const float* wdp = wdn + head * 128 + es * 16;
    float wsr[16], wdr[16];
#pragma unroll
    for (int j = 0; j < 16; ++j) { wsr[j] = wsp[j]; wdr[j] = wdp[j]; }
#pragma unroll
    for (int r = 0; r < 4; ++r) {
      int row = w * 4 + r;
      f16x8 p0 = *(const f16x8*)&Pl[row][es * 16];
      f16x8 p1 = *(const f16x8*)&Pl[row][es * 16 + 8];
      float s1 = 0.f, s2 = 0.f;
#pragma unroll
      for (int j = 0; j < 8; ++j) {
        float v = (float)p0[j];
        s1 += v * wsr[j]; s2 += v * wdr[j];
      }
#pragma unroll
      for (int j = 0; j < 8; ++j) {
        float v = (float)p1[j];
        s1 += v * wsr[8 + j]; s2 += v * wdr[8 + j];
      }
#pragma unroll
      for (int mask = 8; mask <= 32; mask <<= 1) {
        s1 += __shfl_xor(s1, mask);
        s2 += __shfl_xor(s2, mask);
      }
      int nn = r0 + row;
      if (es == 0 && nn < N) { ssrc[nn * 8 + head] = s1; sdst[nn * 8 + head] = s2; }
    }
  }
}

// ---------------- fused tail (layer 1): 32 rows, VGPR<=128, 16-slot ring, nt ----------------

template <typename OutT, bool SC>
__global__ __launch_bounds__(512, 4) void tail1_kernel(const float* __restrict__ Y1,
                                                       const float* __restrict__ w,
                                                       const float* __restrict__ biasA,
                                                       const __half* __restrict__ WtP,
                                                       const float* __restrict__ biasP,
                                                       OutT* __restrict__ out, int N, int NP,
                                                       const float* __restrict__ wsn,
                                                       const float* __restrict__ wdn,
                                                       float* __restrict__ ssrc,
                                                       float* __restrict__ sdst) {
  __shared__ __half Gt[32][1032];
  __shared__ __half Pl[32][136];
  int t = threadIdx.x;
  int r0 = blockIdx.x * 32;
  {
    int c0 = (t & 255) * 4;
    int h = c0 >> 7;
    float4 wa = *(const float4*)&w[c0];
    float4 wb = *(const float4*)&w[1024 + c0];
    float4 wc = *(const float4*)&w[2048 + c0];
    float4 wd = *(const float4*)&w[3072 + c0];
    float4 b4 = *(const float4*)&biasA[c0];
#pragma unroll 4
    for (int r = t >> 8; r < 32; r += 2) {
      float4 yv = *(const float4*)&Y1[((size_t)h * NP + r0 + r) * 4];
      float o0 = gelu_exact(yv.x * wa.x + yv.y * wb.x + yv.z * wc.x + yv.w * wd.x + b4.x);
      float o1 = gelu_exact(yv.x * wa.y + yv.y * wb.y + yv.z * wc.y + yv.w * wd.y + b4.y);
      float o2 = gelu_exact(yv.x * wa.z + yv.y * wb.z + yv.z * wc.z + yv.w * wd.z + b4.z);
      float o3 = gelu_exact(yv.x * wa.w + yv.y * wb.w + yv.z * wc.w + yv.w * wd.w + b4.w);
      Half4 p;
      p.a = __floats2half2_rn(o0, o1);
      p.b = __floats2half2_rn(o2, o3);
      *(Half4*)&Gt[r][c0] = p;
    }
  }
  __syncthreads();
  int wv = t >> 6, lane = t & 63;
  int m = lane & 15, quad = lane >> 4;
  {
    int c0 = wv * 16;
    const __half* pa = WtP + (size_t)wv * 16384 + lane * 8;
    f16x8 ring[16];
#pragma unroll
    for (int u = 0; u < 16; ++u) ring[u] = *(const f16x8*)(pa + u * 512);
    f32x4 acc0 = {0.f, 0.f, 0.f, 0.f}, acc1 = {0.f, 0.f, 0.f, 0.f};
#pragma unroll
    for (int u = 0; u < 32; ++u) {
      int k = u * 32;
      f16x8 av = ring[u & 15];
      f16x8 b0 = *(const f16x8*)&Gt[m][quad * 8 + k];
      f16x8 b1 = *(const f16x8*)&Gt[16 + m][quad * 8 + k];
      acc0 = __builtin_amdgcn_mfma_f32_16x16x32_f16(av, b0, acc0, 0, 0, 0);
      acc1 = __builtin_amdgcn_mfma_f32_16x16x32_f16(av, b1, acc1, 0, 0, 0);
      if (u < 16) ring[u & 15] = *(const f16x8*)(pa + (u + 16) * 512);
    }
    float4 b4 = *(const float4*)&biasP[c0 + quad * 4];
    int row0 = r0 + m, row1 = r0 + 16 + m;
    if constexpr (__is_same(OutT, __half)) {
      Half4 p, q;
      p.a = __floats2half2_rn(acc0[0] + b4.x, acc0[1] + b4.y);
      p.b = __floats2half2_rn(acc0[2] + b4.z, acc0[3] + b4.w);
      q.a = __floats2half2_rn(acc1[0] + b4.x, acc1[1] + b4.y);
      q.b = __floats2half2_rn(acc1[2] + b4.z, acc1[3] + b4.w);
      if constexpr (SC) {
        *(Half4*)&Pl[m][c0 + quad * 4] = p;
        *(Half4*)&Pl[16 + m][c0 + quad * 4] = q;
      }
      if (row0 < N) nt_store8(&out[(size_t)row0 * 128 + c0 + quad * 4], p);
      if (row1 < N) nt_store8(&out[(size_t)row1 * 128 + c0 + quad * 4], q);
    } else {
      if (row0 < N)
        *(float4*)&out[(size_t)row0 * 128 + c0 + quad * 4] =
            make_float4(acc0[0] + b4.x, acc0[1] + b4.y, acc0[2] + b4.z, acc0[3] + b4.w);
      if (row1 < N)
        *(float4*)&out[(size_t)row1 * 128 + c0 + quad * 4] =
            make_float4(acc1[0] + b4.x, acc1[1] + b4.y, acc1[2] + b4.z, acc1[3] + b4.w);
    }
  }
  if constexpr (SC) {
    __syncthreads();
    int head = lane & 7, es = lane >> 3;
    const float* wsp = wsn + head * 128 + es * 16;
    const float* wdp = wdn + head * 128 + es * 16;
    float wsr[16], wdr[16];
#pragma unroll
    for (int j = 0; j < 16; ++j) { wsr[j] = wsp[j]; wdr[j] = wdp[j]; }
#pragma unroll
    for (int r = 0; r < 4; ++r) {
      int row = wv * 4 + r;
      f16x8 p0 = *(const f16x8*)&Pl[row][es * 16];
      f16x8 p1 = *(const f16x8*)&Pl[row][es * 16 + 8];
      float s1 = 0.f, s2 = 0.f;
#pragma unroll
      for (int j = 0; j < 8; ++j) {
        float v = (float)p0[j];
        s1 += v * wsr[j]; s2 += v * wdr[j];
      }
#pragma unroll
      for (int j = 0; j < 8; ++j) {
        float v = (float)p1[j];
        s1 += v * wsr[8 + j]; s2 += v * wdr[8 + j];
      }
#pragma unroll
      for (int mask = 8; mask <= 32; mask <<= 1) {
        s1 += __shfl_xor(s1, mask);
        s2 += __shfl_xor(s2, mask);
      }
      int nn = r0 + row;
      if (es == 0 && nn < N) { ssrc[nn * 8 + head] = s1; sdst[nn * 8 + head] = s2; }
    }
  }
}

// ---------------- PROBES: stage-level ablation with LDS fingerprints ----------------
// V=1 stage1 full | V=2 stage2 only | V=3 stage1 no-gelu | V=4 stage1 no-Wload.
// LDS_Block_Size identifies the variant in the counter table.

template <int V>
__global__ __launch_bounds__(512, 4) void ptail(const __half* Y16,
                                                const __half* WtA,
                                                const float* biasA,
                                                const __half* WtP,
                                                const float* biasP,
                                                __half* outscr, float* scr2,
                                                int N, int NP, int reps) {
  __shared__ __half Gt[32][1032];
  __shared__ char pad[V * 256];
  if (threadIdx.x == 0) pad[V - 1] = (char)reps;   // keep pad allocated
  int w = threadIdx.x >> 6, lane = threadIdx.x & 63;
  int r0 = blockIdx.x * 32;
  int m = lane & 15, quad = lane >> 4;
  float keep = 0.f;
  for (int rep = 0; rep < reps; ++rep) {
    asm volatile("" ::: "memory");
    if constexpr (V == 2) {
      int t = threadIdx.x;
#pragma unroll
      for (int i = 0; i < 16; ++i) {
        int idx = t * 16 + i;
        int row = idx >> 8, col4 = idx & 255;
        Half4 p;
        p.a = __floats2half2_rn(0.01f * ((idx + rep) & 7), 0.01f * ((idx + rep) & 5));
        p.b = __floats2half2_rn(0.01f * ((idx + rep) & 3), 0.01f * (idx & 1));
        *(Half4*)&Gt[row][col4 * 4] = p;
      }
    } else {
      // stage-1 variants
      int h = w;
      const __half* py0 = Y16 + ((size_t)h * NP + r0 + m) * 128 + quad * 8;
      const __half* py1 = py0 + (size_t)16 * 128;
      f16x8 bf0[4], bf1[4];
#pragma unroll
      for (int kk = 0; kk < 4; ++kk) {
        bf0[kk] = __builtin_nontemporal_load((const f16x8*)(py0 + kk * 32));
        bf1[kk] = __builtin_nontemporal_load((const f16x8*)(py1 + kk * 32));
      }
      const __half* wbase = WtA + (size_t)h * 8 * 2048 + lane * 8;
      f16x8 aA[4], aB[4];
      if constexpr (V != 4) {
#pragma unroll
        for (int kk = 0; kk < 4; ++kk) aA[kk] = *(const f16x8*)(wbase + kk * 512);
      } else {
        // synthetic fragments (VALU only, no global load)
        _Float16 seed = (_Float16)(0.001f * (float)(lane + 1));
#pragma unroll
        for (int kk = 0; kk < 4; ++kk)
#pragma unroll
          for (int j = 0; j < 8; ++j) { aA[kk][j] = seed; aB[kk][j] = seed; }
      }
#pragma unroll
      for (int tile = 0; tile < 8; ++tile) {
        if constexpr (V != 4) {
          if (tile < 7) {
            const __half* pn = wbase + (size_t)(tile + 1) * 2048;
            if ((tile & 1) == 0) {
#pragma unroll
              for (int kk = 0; kk < 4; ++kk) aB[kk] = *(const f16x8*)(pn + kk * 512);
            } else {
#pragma unroll
              for (int kk = 0; kk < 4; ++kk) aA[kk] = *(const f16x8*)(pn + kk * 512);
            }
          }
        }
        int gc = w * 128 + tile * 16;
        f32x4 acc0 = {0.f, 0.f, 0.f, 0.f}, acc1 = {0.f, 0.f, 0.f, 0.f};
#pragma unroll
        for (int kk = 0; kk < 4; ++kk) {
          f16x8 av = ((tile & 1) == 0) ? aA[kk] : aB[kk];
          acc0 = __builtin_amdgcn_mfma_f32_16x16x32_f16(av, bf0[kk], acc0, 0, 0, 0);
          acc1 = __builtin_amdgcn_mfma_f32_16x16x32_f16(av, bf1[kk], acc1, 0, 0, 0);
        }
        float4 b4 = *(const float4*)&biasA[gc + quad * 4];
        Half4 p0, p1;
        if constexpr (V == 3) {
          // no gelu
          p0.a = __floats2half2_rn(acc0[0] + b4.x, acc0[1] + b4.y);
          p0.b = __floats2half2_rn(acc0[2] + b4.z, acc0[3] + b4.w);
          p1.a = __floats2half2_rn(acc1[0] + b4.x, acc1[1] + b4.y);
          p1.b = __floats2half2_rn(acc1[2] + b4.z, acc1[3] + b4.w);
        } else {
          p0.a = __floats2half2_rn(gelu_exact(acc0[0] + b4.x), gelu_exact(acc0[1] + b4.y));
          p0.b = __floats2half2_rn(gelu_exact(acc0[2] + b4.z), gelu_exact(acc0[3] + b4.w));
          p1.a = __floats2half2_rn(gelu_exact(acc1[0] + b4.x), gelu_exact(acc1[1] + b4.y));
          p1.b = __floats2half2_rn(gelu_exact(acc1[2] + b4.z), gelu_exact(acc1[3] + b4.w));
        }
        *(Half4*)&Gt[m][gc + quad * 4] = p0;
        *(Half4*)&Gt[16 + m][gc + quad * 4] = p1;
      }
    }
    __syncthreads();
    if constexpr (V == 2) {
      // stage 2 ring GEMM
      int c0 = w * 16;
      const __half* pa = WtP + (size_t)w * 16384 + lane * 8;
      f16x8 ring[16];
#pragma unroll
      for (int u = 0; u < 16; ++u) ring[u] = *(const f16x8*)(pa + u * 512);
      f32x4 acc0 = {0.f, 0.f, 0.f, 0.f}, acc1 = {0.f, 0.f, 0.f, 0.f};
#pragma unroll
      for (int u = 0; u < 32; ++u) {
        int k = u * 32;
        f16x8 av = ring[u & 15];
        f16x8 b0 = *(const f16x8*)&Gt[m][quad * 8 + k];
        f16x8 b1 = *(const f16x8*)&Gt[16 + m][quad * 8 + k];
        acc0 = __builtin_amdgcn_mfma_f32_16x16x32_f16(av, b0, acc0, 0, 0, 0);
        acc1 = __builtin_amdgcn_mfma_f32_16x16x32_f16(av, b1, acc1, 0, 0, 0);
        if (u < 16) ring[u & 15] = *(const f16x8*)(pa + (u + 16) * 512);
      }
      float4 b4 = *(const float4*)&biasP[0 + quad * 4];
      __half* op = outscr + (size_t)(rep & 1) * NP * 128;
      int row0 = r0 + m, row1 = r0 + 16 + m;
      Half4 p, q;
      p.a = __floats2half2_rn(acc0[0] + b4.x, acc0[1] + b4.y);
      p.b = __floats2half2_rn(acc0[2] + b4.z, acc0[3] + b4.w);
      q.a = __floats2half2_rn(acc1[0] + b4.x, acc1[1] + b4.y);
      q.b = __floats2half2_rn(acc1[2] + b4.z, acc1[3] + b4.w);
      if (row0 < N) nt_store8(&op[(size_t)row0 * 128 + w * 16 + quad * 4], p);
      if (row1 < N) nt_store8(&op[(size_t)row1 * 128 + w * 16 + quad * 4], q);
    } else {
      int t = threadIdx.x;
      keep += (float)Gt[t & 31][(t * 2 + rep) & 1023];
      keep += (float)Gt[(t + 7) & 31][(t * 5 + rep * 3) & 1023];
    }
    __syncthreads();
  }
  if constexpr (V != 2)
    scr2[(size_t)blockIdx.x * 512 + threadIdx.x] = keep;
}

// ---------------- orchestration ----------------

extern "C" void kernel_launch(void* const* d_in, const int* in_sizes, int n_in,
                              void* d_out, int out_size, void* d_ws, size_t ws_size,
                              hipStream_t stream) {
  const float* x   = (const float*)d_in[0];
  const int*   ei  = (const int*)d_in[1];
  const float* w1  = (const float*)d_in[2];
  const float* as1 = (const float*)d_in[3];
  const float* ad1 = (const float*)d_in[4];
  const float* b1  = (const float*)d_in[5];
  const float* w2  = (const float*)d_in[6];
  const float* as2 = (const float*)d_in[7];
  const float* ad2 = (const float*)d_in[8];
  const float* b2  = (const float*)d_in[9];
  const float* w3  = (const float*)d_in[10];
  const float* as3 = (const float*)d_in[11];
  const float* ad3 = (const float*)d_in[12];
  const float* b3  = (const float*)d_in[13];
  const float* rw1 = (const float*)d_in[14];
  const float* rb1 = (const float*)d_in[15];
  const float* rw2 = (const float*)d_in[16];
  const float* rb2 = (const float*)d_in[17];
  const float* lw  = (const float*)d_in[18];
  const float* lb  = (const float*)d_in[19];

  int N = in_sizes[0] / 4;
  int E = in_sizes[1] / 2;
  int ET = E + N;
  int nRow32 = (N + 31) / 32;
  int NP = nRow32 * 32;          // padded rows (10016)
  (void)ws_size;

  char* wsb = (char*)d_ws;
  size_t off = 0;
  auto alloc = [&](size_t bytes) -> void* {
    void* p = wsb + off;
    off += (bytes + 255) & ~(size_t)255;
    return p;
  };
  __half* P16  = (__half*)alloc((size_t)N * 128 * 2);
  __half* Y16  = (__half*)alloc((size_t)8 * NP * 128 * 2);
  float*  Y1   = (float*)alloc((size_t)8 * NP * 4 * 4);
  __half* wt2  = (__half*)alloc((size_t)1024 * 128 * 2);
  __half* wt3  = (__half*)alloc((size_t)1024 * 128 * 2);
  __half* rwt1 = (__half*)alloc((size_t)128 * 1024 * 2);
  __half* rwt2 = (__half*)alloc((size_t)128 * 1024 * 2);
  __half* lwt  = (__half*)alloc((size_t)128 * 1024 * 2);
  __half* pscr = (__half*)alloc((size_t)2 * NP * 128 * 2);
  float*  pscr2 = (float*)alloc((size_t)nRow32 * 512 * 4);
  float* ws1 = (float*)alloc(8 * 4 * 4);
  float* wd1 = (float*)alloc(8 * 4 * 4);
  float* ws2 = (float*)alloc(8 * 128 * 4);
  float* wd2 = (float*)alloc(8 * 128 * 4);
  float* ws3 = (float*)alloc(8 * 128 * 4);
  float* wd3 = (float*)alloc(8 * 128 * 4);
  float* ssrc   = (float*)alloc((size_t)N * 8 * 4);
  float* sdst   = (float*)alloc((size_t)N * 8 * 4);
  int* counts  = (int*)alloc((size_t)N * 4);
  int* offsets = (int*)alloc((size_t)(N + 1) * 4);
  int* cursor  = (int*)alloc((size_t)N * 4);
  int* srcs    = (int*)alloc((size_t)ET * 4);

  dim3 blk(THREADS);
  dim3 blk512(512);
  int nHist = (ET + THREADS - 1) / THREADS;

  hipMemsetAsync(counts, 0, (size_t)N * 4, stream);

  prep_kernel<<<dim3(nHist + 640 + 24), blk, 0, stream>>>(
      ei, E, ET, counts,
      w2, w3, rw1, rw2, lw, wt2, wt3, rwt1, rwt2, lwt,
      w1, as1, ad1, as2, ad2, as3, ad3,
      ws1, wd1, ws2, wd2, ws3, wd3, nHist);

  int total1 = N * 8;
  int nSc = (total1 + 1023) / 1024;
  scan_scores_kernel<<<dim3(1 + nSc), dim3(1024), 0, stream>>>(
      counts, offsets, cursor, N, x, ws1, wd1, ssrc, sdst, total1);

  scatter_kernel<<<dim3(nHist), blk, 0, stream>>>(ei, E, ET, cursor, srcs);

  dim3 gNode4(N / 4);
  dim3 gRow32(nRow32);

  // ---- layer 1 ----
  attnagg_x<<<gNode4, blk, 0, stream>>>(x, srcs, offsets, ssrc, sdst, Y1, NP);
  tail1_kernel<__half, true><<<gRow32, blk512, 0, stream>>>(
      Y1, w1, b1, rwt1, rb1, P16, N, NP, ws2, wd2, ssrc, sdst);

  // ---- layer 2 ----
  attnagg_p<<<gNode4, blk, 0, stream>>>(P16, srcs, offsets, ssrc, sdst, Y16, NP);
  tail_mfma<__half, true><<<gRow32, blk512, 0, stream>>>(
      Y16, wt2, b2, rwt2, rb2, P16, N, NP, ws3, wd3, ssrc, sdst);

  // ---- layer 3 ----
  attnagg_p<<<gNode4, blk, 0, stream>>>(P16, srcs, offsets, ssrc, sdst, Y16, NP);
  tail_mfma<float, false><<<gRow32, blk512, 0, stream>>>(
      Y16, wt3, b3, lwt, lb, (float*)d_out, N, NP, nullptr, nullptr, nullptr, nullptr);

  // ---- PROBES (measurement only; scratch outputs; LDS fingerprints) ----
  ptail<1><<<gRow32, blk512, 0, stream>>>(Y16, wt3, b3, lwt, lb, pscr, pscr2, N, NP, 5);
  ptail<2><<<gRow32, blk512, 0, stream>>>(Y16, wt3, b3, lwt, lb, pscr, pscr2, N, NP, 5);
  ptail<3><<<gRow32, blk512, 0, stream>>>(Y16, wt3, b3, lwt, lb, pscr, pscr2, N, NP, 5);
  ptail<4><<<gRow32, blk512, 0, stream>>>(Y16, wt3, b3, lwt, lb, pscr, pscr2, N, NP, 5);
}

// Round 14
// 247.815 us; speedup vs baseline: 2.3132x; 2.3132x over previous
//
#include <hip/hip_runtime.h>
#include <hip/hip_fp16.h>
#include <math.h>

// GAT encoder: N=10000, E=160000 (+N self loops), H=8 heads, C=128, D=1024.
// Best: 241.1us. R29 probes: tail = stage1(15us) + stage2(21us), additive;
// stage1 insensitive to gelu & weight loads. KEY: VGPR_Count=64 despite a
// 16-slot f16x8 ring in source => compiler sank the loads to uses and the
// ring never materialized (~2-4 outstanding) -- why all ILP rounds nulled.
// FETCH 9.5MB/rep for a 256KB weight set => serialized HBM misses.
// R30: pin the pipeline with __builtin_amdgcn_sched_barrier(0):
//   stage2: [16-load cluster] SB [16x(2 MFMA + load u+16)] SB [16x2 MFMA]
//   stage1: per-tile prefetch-issue SB MFMA+gelu body.
// Scheduling-only directive -> bit-identical. Expect tail VGPR ->110+,
// stage2 21->~10us.

#define THREADS 256
#define CAP 128

typedef _Float16 f16x8 __attribute__((ext_vector_type(8)));
typedef float f32x4 __attribute__((ext_vector_type(4)));
typedef float f32x2 __attribute__((ext_vector_type(2)));

struct __align__(8) Half4 { __half2 a, b; };

__device__ __forceinline__ float gelu_exact(float x) {
  return 0.5f * x * (1.0f + erff(x * 0.70710678118654752f));
}

__device__ __forceinline__ void nt_store8(void* dst, const Half4& v) {
  __builtin_nontemporal_store(*(const unsigned long long*)&v,
                              (unsigned long long*)dst);
}

// ---------------- fused prep: hist + weight swizzle/convert + score-vectors ----------------

__global__ __launch_bounds__(256) void prep_kernel(
    const int* __restrict__ ei, int E, int ET, int* __restrict__ counts,
    const float* __restrict__ w2, const float* __restrict__ w3,
    const float* __restrict__ rw1, const float* __restrict__ rw2,
    const float* __restrict__ lw,
    __half* __restrict__ wt2, __half* __restrict__ wt3,
    __half* __restrict__ rwt1, __half* __restrict__ rwt2,
    __half* __restrict__ lwt,
    const float* __restrict__ w1,
    const float* __restrict__ as1, const float* __restrict__ ad1,
    const float* __restrict__ as2, const float* __restrict__ ad2,
    const float* __restrict__ as3, const float* __restrict__ ad3,
    float* __restrict__ ws1, float* __restrict__ wd1,
    float* __restrict__ ws2, float* __restrict__ wd2,
    float* __restrict__ ws3, float* __restrict__ wd3,
    int nHist) {
  __shared__ float tile[32][33];
  int bid = blockIdx.x;
  int t = threadIdx.x;

  if (bid < nHist) {
    int e = bid * 256 + t;
    if (e >= ET) return;
    int d = (e < E) ? ei[E + e] : (e - E);
    atomicAdd(&counts[d], 1);
    return;
  }
  bid -= nHist;
  if (bid < 640) {
    const float* in; __half* out; int K, Ncol;
    int z = bid >> 7, rem = bid & 127;
    switch (z) {
      case 0: in = w2;  out = wt2;  K = 128;  Ncol = 1024; break;
      case 1: in = w3;  out = wt3;  K = 128;  Ncol = 1024; break;
      case 2: in = rw1; out = rwt1; K = 1024; Ncol = 128;  break;
      case 3: in = rw2; out = rwt2; K = 1024; Ncol = 128;  break;
      default: in = lw; out = lwt;  K = 1024; Ncol = 128;  break;
    }
    int kt2, ct2;
    if (z < 2) { kt2 = rem >> 5; ct2 = rem & 31; }
    else       { kt2 = rem & 31; ct2 = rem >> 5; }
    int kb = kt2 * 32, cb = ct2 * 32;
    int KT = K >> 5;
    int tc = t & 31, tr = t >> 5;
#pragma unroll
    for (int r = tr; r < 32; r += 8)
      tile[r][tc] = in[(size_t)(kb + r) * Ncol + cb + tc];
    __syncthreads();
#pragma unroll
    for (int r = tr; r < 32; r += 8) {
      int c = cb + r, k = kb + tc;
      int m = c & 15, ct = c >> 4;
      int j = k & 7, quad = (k >> 3) & 3, kt = k >> 5;
      out[((size_t)(ct * KT + kt) * 64 + quad * 16 + m) * 8 + j] =
          __float2half_rn(tile[tc][r]);
    }
    return;
  }
  bid -= 640;
  {
    int h = bid & 7, yy = bid >> 3;
    int sel = t >> 7;
    int k = t & 127;
    const float* W; const float* av; float* outp; int K;
    switch (yy) {
      case 0: W = w2; av = sel ? ad2 : as2; outp = sel ? wd2 : ws2; K = 128; break;
      case 1: W = w3; av = sel ? ad3 : as3; outp = sel ? wd3 : ws3; K = 128; break;
      default: W = w1; av = sel ? ad1 : as1; outp = sel ? wd1 : ws1; K = 4; break;
    }
    if (k >= K) return;
    const float* wrow = W + (size_t)k * 1024 + h * 128;
    const float* arow = av + h * 128;
    float s = 0.f;
    for (int c = 0; c < 128; c += 4) {
      float4 wv = *(const float4*)&wrow[c];
      float4 a4 = *(const float4*)&arow[c];
      s += wv.x * a4.x + wv.y * a4.y + wv.z * a4.z + wv.w * a4.w;
    }
    outp[h * K + k] = s;
  }
}

// ---------------- scan (block 0) || layer-1 scores (blocks 1..) ----------------

__global__ __launch_bounds__(1024) void scan_scores_kernel(
    const int* __restrict__ counts, int* __restrict__ offsets,
    int* __restrict__ cursor, int n,
    const float* __restrict__ x,
    const float* __restrict__ ws1, const float* __restrict__ wd1,
    float* __restrict__ ssrc, float* __restrict__ sdst, int total) {
  __shared__ int sums[1024];
  if (blockIdx.x == 0) {
    int t = threadIdx.x;
    int per = (n + 1023) >> 10;
    int start = t * per; if (start > n) start = n;
    int end = start + per; if (end > n) end = n;
    int local = 0;
    for (int i = start; i < end; ++i) local += counts[i];
    sums[t] = local;
    __syncthreads();
    for (int off = 1; off < 1024; off <<= 1) {
      int add = (t >= off) ? sums[t - off] : 0;
      __syncthreads();
      sums[t] += add;
      __syncthreads();
    }
    int run = (t == 0) ? 0 : sums[t - 1];
    for (int i = start; i < end; ++i) {
      offsets[i] = run; cursor[i] = run; run += counts[i];
    }
    if (t == 1023) offsets[n] = run;
    return;
  }
  int idx = (blockIdx.x - 1) * 1024 + threadIdx.x;
  if (idx >= total) return;
  int nn = idx >> 3, h = idx & 7;
  float4 xv = *(const float4*)&x[nn * 4];
  float4 a = *(const float4*)&ws1[h * 4];
  float4 b = *(const float4*)&wd1[h * 4];
  ssrc[idx] = xv.x * a.x + xv.y * a.y + xv.z * a.z + xv.w * a.w;
  sdst[idx] = xv.x * b.x + xv.y * b.y + xv.z * b.z + xv.w * b.w;
}

__global__ void scatter_kernel(const int* __restrict__ ei, int E, int ET,
                               int* __restrict__ cursor, int* __restrict__ srcs) {
  int e = blockIdx.x * THREADS + threadIdx.x;
  if (e >= ET) return;
  int s = (e < E) ? ei[e] : (e - E);
  int d = (e < E) ? ei[E + e] : (e - E);
  int pos = atomicAdd(&cursor[d], 1);
  srcs[pos] = s;
}

// ---------------- fused attention + aggregation (P16), wave per node ----------------

__global__ __launch_bounds__(256) void attnagg_p(const __half* __restrict__ P16,
                                                 const int* __restrict__ srcs,
                                                 const int* __restrict__ offsets,
                                                 const float* __restrict__ ssrc,
                                                 const float* __restrict__ sdst,
                                                 __half* __restrict__ Y16, int NP) {
  __shared__ float lal[4][CAP][8];
  __shared__ int ls[4][CAP];
  __shared__ float szinv[4][8];
  int w = threadIdx.x >> 6, lane = threadIdx.x & 63;
  int n = blockIdx.x * 4 + w;
  int start = offsets[n], deg = offsets[n + 1] - start;
  int head = lane & 7, es = lane >> 3;
  float sd = sdst[n * 8 + head];
  int c2 = lane * 2;
  const __half* pbase = P16 + c2;
  f32x2 acc2[8] = {};
  float s = 0.f;
  for (int cc = 0; cc < deg; cc += CAP) {
    int cm = min(CAP, deg - cc);
    for (int i = es; i < cm; i += 8) {
      int sp = srcs[start + cc + i];
      float v = ssrc[sp * 8 + head] + sd;
      v = (v > 0.f) ? v : 0.2f * v;
      float e = __expf(v);
      lal[w][i][head] = e;
      if (head == 0) ls[w][i] = sp;
      s += e;
    }
    int i = 0;
    for (; i + 8 <= cm; i += 8) {
      f32x2 pp[8];
#pragma unroll
      for (int u = 0; u < 8; ++u) {
        int sp = ls[w][i + u];
        float2 f = __half22float2(*(const __half2*)&pbase[(size_t)sp * 128]);
        pp[u].x = f.x; pp[u].y = f.y;
      }
#pragma unroll
      for (int u = 0; u < 8; ++u) {
        float4 a00 = *(float4*)&lal[w][i + u][0];
        float4 a01 = *(float4*)&lal[w][i + u][4];
        float a0[8] = {a00.x, a00.y, a00.z, a00.w, a01.x, a01.y, a01.z, a01.w};
#pragma unroll
        for (int h = 0; h < 8; ++h) acc2[h] += a0[h] * pp[u];
      }
    }
    for (; i < cm; ++i) {
      int sp0 = ls[w][i];
      float2 f = __half22float2(*(const __half2*)&pbase[(size_t)sp0 * 128]);
      f32x2 p0; p0.x = f.x; p0.y = f.y;
      float4 a00 = *(float4*)&lal[w][i][0];
      float4 a01 = *(float4*)&lal[w][i][4];
      float a0[8] = {a00.x, a00.y, a00.z, a00.w, a01.x, a01.y, a01.z, a01.w};
#pragma unroll
      for (int h = 0; h < 8; ++h) acc2[h] += a0[h] * p0;
    }
  }
#pragma unroll
  for (int mask = 8; mask <= 32; mask <<= 1)
    s += __shfl_xor(s, mask);
  if (es == 0) szinv[w][head] = 1.f / s;
#pragma unroll
  for (int h = 0; h < 8; ++h) {
    float zi = szinv[w][h];
    __half2 hv = __floats2half2_rn(acc2[h].x * zi, acc2[h].y * zi);
    __builtin_nontemporal_store(*(const unsigned int*)&hv,
        (unsigned int*)&Y16[((size_t)h * NP + n) * 128 + c2]);
  }
}

// ---------------- fused attention + aggregation (layer 1, raw x) ----------------

__global__ __launch_bounds__(256) void attnagg_x(const float* __restrict__ x,
                                                 const int* __restrict__ srcs,
                                                 const int* __restrict__ offsets,
                                                 const float* __restrict__ ssrc,
                                                 const float* __restrict__ sdst,
                                                 float* __restrict__ Y1, int NP) {
  __shared__ float lal[4][CAP][8];
  __shared__ int ls[4][CAP];
  __shared__ float szinv[4][8];
  int w = threadIdx.x >> 6, lane = threadIdx.x & 63;
  int n = blockIdx.x * 4 + w;
  int start = offsets[n], deg = offsets[n + 1] - start;
  int head = lane & 7, es = lane >> 3;
  float sd = sdst[n * 8 + head];
  int eo = lane >> 5, hb = (lane >> 2) & 7, ch = lane & 3;
  float acc = 0.f;
  float s = 0.f;
  for (int cc = 0; cc < deg; cc += CAP) {
    int cm = min(CAP, deg - cc);
    for (int i = es; i < cm; i += 8) {
      int sp = srcs[start + cc + i];
      float v = ssrc[sp * 8 + head] + sd;
      v = (v > 0.f) ? v : 0.2f * v;
      float e = __expf(v);
      lal[w][i][head] = e;
      if (head == 0) ls[w][i] = sp;
      s += e;
    }
    int i = eo;
    for (; i + 6 < cm; i += 8) {
      float xv[4]; float av[4];
#pragma unroll
      for (int u = 0; u < 4; ++u) {
        int sp = ls[w][i + 2 * u];
        xv[u] = x[sp * 4 + ch];
      }
#pragma unroll
      for (int u = 0; u < 4; ++u) av[u] = lal[w][i + 2 * u][hb];
#pragma unroll
      for (int u = 0; u < 4; ++u) acc += av[u] * xv[u];
    }
    for (; i < cm; i += 2) {
      int sp = ls[w][i];
      acc += lal[w][i][hb] * x[sp * 4 + ch];
    }
  }
#pragma unroll
  for (int mask = 8; mask <= 32; mask <<= 1)
    s += __shfl_xor(s, mask);
  if (es == 0) szinv[w][head] = 1.f / s;
  acc += __shfl_xor(acc, 32);
  if (lane < 32) {
    float zi = szinv[w][hb];
    Y1[((size_t)hb * NP + n) * 4 + ch] = acc * zi;
  }
}

// ---------------- fused tail (layers 2/3): 32 rows, pinned load clusters ----------------

template <typename OutT, bool SC>
__global__ __launch_bounds__(512, 4) void tail_mfma(const __half* __restrict__ Y16,
                                                    const __half* __restrict__ WtA,
                                                    const float* __restrict__ biasA,
                                                    const __half* __restrict__ WtP,
                                                    const float* __restrict__ biasP,
                                                    OutT* __restrict__ out, int N, int NP,
                                                    const float* __restrict__ wsn,
                                                    const float* __restrict__ wdn,
                                                    float* __restrict__ ssrc,
                                                    float* __restrict__ sdst) {
  __shared__ __half Gt[32][1032];
  __shared__ __half Pl[32][136];
  int w = threadIdx.x >> 6, lane = threadIdx.x & 63;
  int r0 = blockIdx.x * 32;
  int m = lane & 15, quad = lane >> 4;
  // stage 1: per-tile prefetch issue pinned before MFMA+gelu body
  {
    int h = w;
    const __half* py0 = Y16 + ((size_t)h * NP + r0 + m) * 128 + quad * 8;
    const __half* py1 = py0 + (size_t)16 * 128;
    f16x8 bf0[4], bf1[4];
#pragma unroll
    for (int kk = 0; kk < 4; ++kk) {
      bf0[kk] = __builtin_nontemporal_load((const f16x8*)(py0 + kk * 32));
      bf1[kk] = __builtin_nontemporal_load((const f16x8*)(py1 + kk * 32));
    }
    const __half* wbase = WtA + (size_t)h * 8 * 2048 + lane * 8;
    f16x8 aA[4], aB[4];
#pragma unroll
    for (int kk = 0; kk < 4; ++kk) aA[kk] = *(const f16x8*)(wbase + kk * 512);
#pragma unroll
    for (int tile = 0; tile < 8; ++tile) {
      if (tile < 7) {
        const __half* pn = wbase + (size_t)(tile + 1) * 2048;
        if ((tile & 1) == 0) {
#pragma unroll
          for (int kk = 0; kk < 4; ++kk) aB[kk] = *(const f16x8*)(pn + kk * 512);
        } else {
#pragma unroll
          for (int kk = 0; kk < 4; ++kk) aA[kk] = *(const f16x8*)(pn + kk * 512);
        }
      }
      __builtin_amdgcn_sched_barrier(0);   // pin prefetch issue above MFMAs
      int gc = w * 128 + tile * 16;
      f32x4 acc0 = {0.f, 0.f, 0.f, 0.f}, acc1 = {0.f, 0.f, 0.f, 0.f};
#pragma unroll
      for (int kk = 0; kk < 4; ++kk) {
        f16x8 av = ((tile & 1) == 0) ? aA[kk] : aB[kk];
        acc0 = __builtin_amdgcn_mfma_f32_16x16x32_f16(av, bf0[kk], acc0, 0, 0, 0);
        acc1 = __builtin_amdgcn_mfma_f32_16x16x32_f16(av, bf1[kk], acc1, 0, 0, 0);
      }
      float4 b4 = *(const float4*)&biasA[gc + quad * 4];
      Half4 p0, p1;
      p0.a = __floats2half2_rn(gelu_exact(acc0[0] + b4.x), gelu_exact(acc0[1] + b4.y));
      p0.b = __floats2half2_rn(gelu_exact(acc0[2] + b4.z), gelu_exact(acc0[3] + b4.w));
      p1.a = __floats2half2_rn(gelu_exact(acc1[0] + b4.x), gelu_exact(acc1[1] + b4.y));
      p1.b = __floats2half2_rn(gelu_exact(acc1[2] + b4.z), gelu_exact(acc1[3] + b4.w));
      *(Half4*)&Gt[m][gc + quad * 4] = p0;
      *(Half4*)&Gt[16 + m][gc + quad * 4] = p1;
    }
  }
  __syncthreads();
  // stage 2: pinned 16-load cluster, then overlap second half
  {
    int c0 = w * 16;
    const __half* pa = WtP + (size_t)w * 16384 + lane * 8;
    f16x8 ring[16];
#pragma unroll
    for (int u = 0; u < 16; ++u) ring[u] = *(const f16x8*)(pa + u * 512);
    __builtin_amdgcn_sched_barrier(0);     // 16 loads issued before any MFMA
    f32x4 acc0 = {0.f, 0.f, 0.f, 0.f}, acc1 = {0.f, 0.f, 0.f, 0.f};
#pragma unroll
    for (int u = 0; u < 16; ++u) {
      int k = u * 32;
      f16x8 av = ring[u];
      f16x8 b0 = *(const f16x8*)&Gt[m][quad * 8 + k];
      f16x8 b1 = *(const f16x8*)&Gt[16 + m][quad * 8 + k];
      acc0 = __builtin_amdgcn_mfma_f32_16x16x32_f16(av, b0, acc0, 0, 0, 0);
      acc1 = __builtin_amdgcn_mfma_f32_16x16x32_f16(av, b1, acc1, 0, 0, 0);
      ring[u] = *(const f16x8*)(pa + (u + 16) * 512);
    }
    __builtin_amdgcn_sched_barrier(0);     // second-half loads stay above
#pragma unroll
    for (int u = 16; u < 32; ++u) {
      int k = u * 32;
      f16x8 av = ring[u - 16];
      f16x8 b0 = *(const f16x8*)&Gt[m][quad * 8 + k];
      f16x8 b1 = *(const f16x8*)&Gt[16 + m][quad * 8 + k];
      acc0 = __builtin_amdgcn_mfma_f32_16x16x32_f16(av, b0, acc0, 0, 0, 0);
      acc1 = __builtin_amdgcn_mfma_f32_16x16x32_f16(av, b1, acc1, 0, 0, 0);
    }
    float4 b4 = *(const float4*)&biasP[c0 + quad * 4];
    int row0 = r0 + m, row1 = r0 + 16 + m;
    if constexpr (__is_same(OutT, __half)) {
      Half4 p, q;
      p.a = __floats2half2_rn(acc0[0] + b4.x, acc0[1] + b4.y);
      p.b = __floats2half2_rn(acc0[2] + b4.z, acc0[3] + b4.w);
      q.a = __floats2half2_rn(acc1[0] + b4.x, acc1[1] + b4.y);
      q.b = __floats2half2_rn(acc1[2] + b4.z, acc1[3] + b4.w);
      if constexpr (SC) {
        *(Half4*)&Pl[m][c0 + quad * 4] = p;
        *(Half4*)&Pl[16 + m][c0 + quad * 4] = q;
      }
      if (row0 < N) nt_store8(&out[(size_t)row0 * 128 + c0 + quad * 4], p);
      if (row1 < N) nt_store8(&out[(size_t)row1 * 128 + c0 + quad * 4], q);
    } else {
      if (row0 < N)
        *(float4*)&out[(size_t)row0 * 128 + c0 + quad * 4] =
            make_float4(acc0[0] + b4.x, acc0[1] + b4.y, acc0[2] + b4.z, acc0[3] + b4.w);
      if (row1 < N)
        *(float4*)&out[(size_t)row1 * 128 + c0 + quad * 4] =
            make_float4(acc1[0] + b4.x, acc1[1] + b4.y, acc1[2] + b4.z, acc1[3] + b4.w);
    }
  }
  if constexpr (SC) {
    __syncthreads();
    int head = lane & 7, es = lane >> 3;
    const float* wsp = wsn + head * 128 + es * 16;
    const float* wdp = wdn + head * 128 + es * 16;
    float wsr[16], wdr[16];
#pragma unroll
    for (int j = 0; j < 16; ++j) { wsr[j] = wsp[j]; wdr[j] = wdp[j]; }
#pragma unroll
    for (int r = 0; r < 4; ++r) {
      int row = w * 4 + r;
      f16x8 p0 = *(const f16x8*)&Pl[row][es * 16];
      f16x8 p1 = *(const f16x8*)&Pl[row][es * 16 + 8];
      float s1 = 0.f, s2 = 0.f;
#pragma unroll
      for (int j = 0; j < 8; ++j) {
        float v = (float)p0[j];
        s1 += v * wsr[j]; s2 += v * wdr[j];
      }
#pragma unroll
      for (int j = 0; j < 8; ++j) {
        float v = (float)p1[j];
        s1 += v * wsr[8 + j]; s2 += v * wdr[8 + j];
      }
#pragma unroll
      for (int mask = 8; mask <= 32; mask <<= 1) {
        s1 += __shfl_xor(s1, mask);
        s2 += __shfl_xor(s2, mask);
      }
      int nn = r0 + row;
      if (es == 0 && nn < N) { ssrc[nn * 8 + head] = s1; sdst[nn * 8 + head] = s2; }
    }
  }
}

// ---------------- fused tail (layer 1): 32 rows, pinned load clusters ----------------

template <typename OutT, bool SC>
__global__ __launch_bounds__(512, 4) void tail1_kernel(const float* __restrict__ Y1,
                                                       const float* __restrict__ w,
                                                       const float* __restrict__ biasA,
                                                       const __half* __restrict__ WtP,
                                                       const float* __restrict__ biasP,
                                                       OutT* __restrict__ out, int N, int NP,
                                                       const float* __restrict__ wsn,
                                                       const float* __restrict__ wdn,
                                                       float* __restrict__ ssrc,
                                                       float* __restrict__ sdst) {
  __shared__ __half Gt[32][1032];
  __shared__ __half Pl[32][136];
  int t = threadIdx.x;
  int r0 = blockIdx.x * 32;
  {
    int c0 = (t & 255) * 4;
    int h = c0 >> 7;
    float4 wa = *(const float4*)&w[c0];
    float4 wb = *(const float4*)&w[1024 + c0];
    float4 wc = *(const float4*)&w[2048 + c0];
    float4 wd = *(const float4*)&w[3072 + c0];
    float4 b4 = *(const float4*)&biasA[c0];
#pragma unroll 4
    for (int r = t >> 8; r < 32; r += 2) {
      float4 yv = *(const float4*)&Y1[((size_t)h * NP + r0 + r) * 4];
      float o0 = gelu_exact(yv.x * wa.x + yv.y * wb.x + yv.z * wc.x + yv.w * wd.x + b4.x);
      float o1 = gelu_exact(yv.x * wa.y + yv.y * wb.y + yv.z * wc.y + yv.w * wd.y + b4.y);
      float o2 = gelu_exact(yv.x * wa.z + yv.y * wb.z + yv.z * wc.z + yv.w * wd.z + b4.z);
      float o3 = gelu_exact(yv.x * wa.w + yv.y * wb.w + yv.z * wc.w + yv.w * wd.w + b4.w);
      Half4 p;
      p.a = __floats2half2_rn(o0, o1);
      p.b = __floats2half2_rn(o2, o3);
      *(Half4*)&Gt[r][c0] = p;
    }
  }
  __syncthreads();
  int wv = t >> 6, lane = t & 63;
  int m = lane & 15, quad = lane >> 4;
  {
    int c0 = wv * 16;
    const __half* pa = WtP + (size_t)wv * 16384 + lane * 8;
    f16x8 ring[16];
#pragma unroll
    for (int u = 0; u < 16; ++u) ring[u] = *(const f16x8*)(pa + u * 512);
    __builtin_amdgcn_sched_barrier(0);
    f32x4 acc0 = {0.f, 0.f, 0.f, 0.f}, acc1 = {0.f, 0.f, 0.f, 0.f};
#pragma unroll
    for (int u = 0; u < 16; ++u) {
      int k = u * 32;
      f16x8 av = ring[u];
      f16x8 b0 = *(const f16x8*)&Gt[m][quad * 8 + k];
      f16x8 b1 = *(const f16x8*)&Gt[16 + m][quad * 8 + k];
      acc0 = __builtin_amdgcn_mfma_f32_16x16x32_f16(av, b0, acc0, 0, 0, 0);
      acc1 = __builtin_amdgcn_mfma_f32_16x16x32_f16(av, b1, acc1, 0, 0, 0);
      ring[u] = *(const f16x8*)(pa + (u + 16) * 512);
    }
    __builtin_amdgcn_sched_barrier(0);
#pragma unroll
    for (int u = 16; u < 32; ++u) {
      int k = u * 32;
      f16x8 av = ring[u - 16];
      f16x8 b0 = *(const f16x8*)&Gt[m][quad * 8 + k];
      f16x8 b1 = *(const f16x8*)&Gt[16 + m][quad * 8 + k];
      acc0 = __builtin_amdgcn_mfma_f32_16x16x32_f16(av, b0, acc0, 0, 0, 0);
      acc1 = __builtin_amdgcn_mfma_f32_16x16x32_f16(av, b1, acc1, 0, 0, 0);
    }
    float4 b4 = *(const float4*)&biasP[c0 + quad * 4];
    int row0 = r0 + m, row1 = r0 + 16 + m;
    if constexpr (__is_same(OutT, __half)) {
      Half4 p, q;
      p.a = __floats2half2_rn(acc0[0] + b4.x, acc0[1] + b4.y);
      p.b = __floats2half2_rn(acc0[2] + b4.z, acc0[3] + b4.w);
      q.a = __floats2half2_rn(acc1[0] + b4.x, acc1[1] + b4.y);
      q.b = __floats2half2_rn(acc1[2] + b4.z, acc1[3] + b4.w);
      if constexpr (SC) {
        *(Half4*)&Pl[m][c0 + quad * 4] = p;
        *(Half4*)&Pl[16 + m][c0 + quad * 4] = q;
      }
      if (row0 < N) nt_store8(&out[(size_t)row0 * 128 + c0 + quad * 4], p);
      if (row1 < N) nt_store8(&out[(size_t)row1 * 128 + c0 + quad * 4], q);
    } else {
      if (row0 < N)
        *(float4*)&out[(size_t)row0 * 128 + c0 + quad * 4] =
            make_float4(acc0[0] + b4.x, acc0[1] + b4.y, acc0[2] + b4.z, acc0[3] + b4.w);
      if (row1 < N)
        *(float4*)&out[(size_t)row1 * 128 + c0 + quad * 4] =
            make_float4(acc1[0] + b4.x, acc1[1] + b4.y, acc1[2] + b4.z, acc1[3] + b4.w);
    }
  }
  if constexpr (SC) {
    __syncthreads();
    int head = lane & 7, es = lane >> 3;
    const float* wsp = wsn + head * 128 + es * 16;
    const float* wdp = wdn + head * 128 + es * 16;
    float wsr[16], wdr[16];
#pragma unroll
    for (int j = 0; j < 16; ++j) { wsr[j] = wsp[j]; wdr[j] = wdp[j]; }
#pragma unroll
    for (int r = 0; r < 4; ++r) {
      int row = wv * 4 + r;
      f16x8 p0 = *(const f16x8*)&Pl[row][es * 16];
      f16x8 p1 = *(const f16x8*)&Pl[row][es * 16 + 8];
      float s1 = 0.f, s2 = 0.f;
#pragma unroll
      for (int j = 0; j < 8; ++j) {
        float v = (float)p0[j];
        s1 += v * wsr[j]; s2 += v * wdr[j];
      }
#pragma unroll
      for (int j = 0; j < 8; ++j) {
        float v = (float)p1[j];
        s1 += v * wsr[8 + j]; s2 += v * wdr[8 + j];
      }
#pragma unroll
      for (int mask = 8; mask <= 32; mask <<= 1) {
        s1 += __shfl_xor(s1, mask);
        s2 += __shfl_xor(s2, mask);
      }
      int nn = r0 + row;
      if (es == 0 && nn < N) { ssrc[nn * 8 + head] = s1; sdst[nn * 8 + head] = s2; }
    }
  }
}

// ---------------- orchestration ----------------

extern "C" void kernel_launch(void* const* d_in, const int* in_sizes, int n_in,
                              void* d_out, int out_size, void* d_ws, size_t ws_size,
                              hipStream_t stream) {
  const float* x   = (const float*)d_in[0];
  const int*   ei  = (const int*)d_in[1];
  const float* w1  = (const float*)d_in[2];
  const float* as1 = (const float*)d_in[3];
  const float* ad1 = (const float*)d_in[4];
  const float* b1  = (const float*)d_in[5];
  const float* w2  = (const float*)d_in[6];
  const float* as2 = (const float*)d_in[7];
  const float* ad2 = (const float*)d_in[8];
  const float* b2  = (const float*)d_in[9];
  const float* w3  = (const float*)d_in[10];
  const float* as3 = (const float*)d_in[11];
  const float* ad3 = (const float*)d_in[12];
  const float* b3  = (const float*)d_in[13];
  const float* rw1 = (const float*)d_in[14];
  const float* rb1 = (const float*)d_in[15];
  const float* rw2 = (const float*)d_in[16];
  const float* rb2 = (const float*)d_in[17];
  const float* lw  = (const float*)d_in[18];
  const float* lb  = (const float*)d_in[19];

  int N = in_sizes[0] / 4;
  int E = in_sizes[1] / 2;
  int ET = E + N;
  int nRow32 = (N + 31) / 32;
  int NP = nRow32 * 32;          // padded rows (10016)
  (void)ws_size;

  char* wsb = (char*)d_ws;
  size_t off = 0;
  auto alloc = [&](size_t bytes) -> void* {
    void* p = wsb + off;
    off += (bytes + 255) & ~(size_t)255;
    return p;
  };
  __half* P16  = (__half*)alloc((size_t)N * 128 * 2);
  __half* Y16  = (__half*)alloc((size_t)8 * NP * 128 * 2);
  float*  Y1   = (float*)alloc((size_t)8 * NP * 4 * 4);
  __half* wt2  = (__half*)alloc((size_t)1024 * 128 * 2);
  __half* wt3  = (__half*)alloc((size_t)1024 * 128 * 2);
  __half* rwt1 = (__half*)alloc((size_t)128 * 1024 * 2);
  __half* rwt2 = (__half*)alloc((size_t)128 * 1024 * 2);
  __half* lwt  = (__half*)alloc((size_t)128 * 1024 * 2);
  float* ws1 = (float*)alloc(8 * 4 * 4);
  float* wd1 = (float*)alloc(8 * 4 * 4);
  float* ws2 = (float*)alloc(8 * 128 * 4);
  float* wd2 = (float*)alloc(8 * 128 * 4);
  float* ws3 = (float*)alloc(8 * 128 * 4);
  float* wd3 = (float*)alloc(8 * 128 * 4);
  float* ssrc   = (float*)alloc((size_t)N * 8 * 4);
  float* sdst   = (float*)alloc((size_t)N * 8 * 4);
  int* counts  = (int*)alloc((size_t)N * 4);
  int* offsets = (int*)alloc((size_t)(N + 1) * 4);
  int* cursor  = (int*)alloc((size_t)N * 4);
  int* srcs    = (int*)alloc((size_t)ET * 4);

  dim3 blk(THREADS);
  dim3 blk512(512);
  int nHist = (ET + THREADS - 1) / THREADS;

  hipMemsetAsync(counts, 0, (size_t)N * 4, stream);

  prep_kernel<<<dim3(nHist + 640 + 24), blk, 0, stream>>>(
      ei, E, ET, counts,
      w2, w3, rw1, rw2, lw, wt2, wt3, rwt1, rwt2, lwt,
      w1, as1, ad1, as2, ad2, as3, ad3,
      ws1, wd1, ws2, wd2, ws3, wd3, nHist);

  int total1 = N * 8;
  int nSc = (total1 + 1023) / 1024;
  scan_scores_kernel<<<dim3(1 + nSc), dim3(1024), 0, stream>>>(
      counts, offsets, cursor, N, x, ws1, wd1, ssrc, sdst, total1);

  scatter_kernel<<<dim3(nHist), blk, 0, stream>>>(ei, E, ET, cursor, srcs);

  dim3 gNode4(N / 4);
  dim3 gRow32(nRow32);

  // ---- layer 1 ----
  attnagg_x<<<gNode4, blk, 0, stream>>>(x, srcs, offsets, ssrc, sdst, Y1, NP);
  tail1_kernel<__half, true><<<gRow32, blk512, 0, stream>>>(
      Y1, w1, b1, rwt1, rb1, P16, N, NP, ws2, wd2, ssrc, sdst);

  // ---- layer 2 ----
  attnagg_p<<<gNode4, blk, 0, stream>>>(P16, srcs, offsets, ssrc, sdst, Y16, NP);
  tail_mfma<__half, true><<<gRow32, blk512, 0, stream>>>(
      Y16, wt2, b2, rwt2, rb2, P16, N, NP, ws3, wd3, ssrc, sdst);

  // ---- layer 3 ----
  attnagg_p<<<gNode4, blk, 0, stream>>>(P16, srcs, offsets, ssrc, sdst, Y16, NP);
  tail_mfma<float, false><<<gRow32, blk512, 0, stream>>>(
      Y16, wt3, b3, lwt, lb, (float*)d_out, N, NP, nullptr, nullptr, nullptr, nullptr);
}

// Round 15
// 241.028 us; speedup vs baseline: 2.3783x; 1.0282x over previous
//
#include <hip/hip_runtime.h>
#include <hip/hip_fp16.h>
#include <math.h>

// GAT encoder: N=10000, E=160000 (+N self loops), H=8 heads, C=128, D=1024.
// Session best = 241.1us (this config, R25/R9): fused prep + scan||scores +
// scores-in-tail + wave-per-node attnagg (batch-8 gather, packed f32x2 fma)
// + swizzled fragment-interleaved weights + 32-row tails (VGPR<=128).
// Falsified levers (kept OUT): megafusion (R18, latency-bound), tail split
// (R27, +49us), 16-row re-grid (R21, 2x weight traffic), 32-deep preload /
// 16-ring / nt-hints / sched_barrier (R24/25/28/30: compiler sinks loads,
// VGPR stays 52, all neutral -- m131-m141 reproduced). Remaining headroom
// (~tails 105us vs ~10 ideal) needs counted-vmcnt async staging (T3/T4),
// a new sync template requiring race screening unavailable headlessly.

#define THREADS 256
#define CAP 128

typedef _Float16 f16x8 __attribute__((ext_vector_type(8)));
typedef float f32x4 __attribute__((ext_vector_type(4)));
typedef float f32x2 __attribute__((ext_vector_type(2)));

struct __align__(8) Half4 { __half2 a, b; };

__device__ __forceinline__ float gelu_exact(float x) {
  return 0.5f * x * (1.0f + erff(x * 0.70710678118654752f));
}

// ---------------- fused prep: hist + weight swizzle/convert + score-vectors ----------------
// Weight layout (fragment-interleaved): A[c][k] = in[k][c]; tile ct=c>>4,
// kt=k>>5; lane = ((k>>3)&3)*16 + (c&15); j = k&7:
//   out[((ct*KT + kt)*64 + lane)*8 + j],  KT = K/32.

__global__ __launch_bounds__(256) void prep_kernel(
    const int* __restrict__ ei, int E, int ET, int* __restrict__ counts,
    const float* __restrict__ w2, const float* __restrict__ w3,
    const float* __restrict__ rw1, const float* __restrict__ rw2,
    const float* __restrict__ lw,
    __half* __restrict__ wt2, __half* __restrict__ wt3,
    __half* __restrict__ rwt1, __half* __restrict__ rwt2,
    __half* __restrict__ lwt,
    const float* __restrict__ w1,
    const float* __restrict__ as1, const float* __restrict__ ad1,
    const float* __restrict__ as2, const float* __restrict__ ad2,
    const float* __restrict__ as3, const float* __restrict__ ad3,
    float* __restrict__ ws1, float* __restrict__ wd1,
    float* __restrict__ ws2, float* __restrict__ wd2,
    float* __restrict__ ws3, float* __restrict__ wd3,
    int nHist) {
  __shared__ float tile[32][33];
  int bid = blockIdx.x;
  int t = threadIdx.x;

  if (bid < nHist) {
    int e = bid * 256 + t;
    if (e >= ET) return;
    int d = (e < E) ? ei[E + e] : (e - E);
    atomicAdd(&counts[d], 1);
    return;
  }
  bid -= nHist;
  if (bid < 640) {
    const float* in; __half* out; int K, Ncol;
    int z = bid >> 7, rem = bid & 127;
    switch (z) {
      case 0: in = w2;  out = wt2;  K = 128;  Ncol = 1024; break;
      case 1: in = w3;  out = wt3;  K = 128;  Ncol = 1024; break;
      case 2: in = rw1; out = rwt1; K = 1024; Ncol = 128;  break;
      case 3: in = rw2; out = rwt2; K = 1024; Ncol = 128;  break;
      default: in = lw; out = lwt;  K = 1024; Ncol = 128;  break;
    }
    int kt2, ct2;
    if (z < 2) { kt2 = rem >> 5; ct2 = rem & 31; }
    else       { kt2 = rem & 31; ct2 = rem >> 5; }
    int kb = kt2 * 32, cb = ct2 * 32;
    int KT = K >> 5;
    int tc = t & 31, tr = t >> 5;
#pragma unroll
    for (int r = tr; r < 32; r += 8)
      tile[r][tc] = in[(size_t)(kb + r) * Ncol + cb + tc];
    __syncthreads();
#pragma unroll
    for (int r = tr; r < 32; r += 8) {
      int c = cb + r, k = kb + tc;
      int m = c & 15, ct = c >> 4;
      int j = k & 7, quad = (k >> 3) & 3, kt = k >> 5;
      out[((size_t)(ct * KT + kt) * 64 + quad * 16 + m) * 8 + j] =
          __float2half_rn(tile[tc][r]);
    }
    return;
  }
  bid -= 640;
  {
    int h = bid & 7, yy = bid >> 3;
    int sel = t >> 7;
    int k = t & 127;
    const float* W; const float* av; float* outp; int K;
    switch (yy) {
      case 0: W = w2; av = sel ? ad2 : as2; outp = sel ? wd2 : ws2; K = 128; break;
      case 1: W = w3; av = sel ? ad3 : as3; outp = sel ? wd3 : ws3; K = 128; break;
      default: W = w1; av = sel ? ad1 : as1; outp = sel ? wd1 : ws1; K = 4; break;
    }
    if (k >= K) return;
    const float* wrow = W + (size_t)k * 1024 + h * 128;
    const float* arow = av + h * 128;
    float s = 0.f;
    for (int c = 0; c < 128; c += 4) {
      float4 wv = *(const float4*)&wrow[c];
      float4 a4 = *(const float4*)&arow[c];
      s += wv.x * a4.x + wv.y * a4.y + wv.z * a4.z + wv.w * a4.w;
    }
    outp[h * K + k] = s;
  }
}

// ---------------- scan (block 0) || layer-1 scores (blocks 1..) ----------------

__global__ __launch_bounds__(1024) void scan_scores_kernel(
    const int* __restrict__ counts, int* __restrict__ offsets,
    int* __restrict__ cursor, int n,
    const float* __restrict__ x,
    const float* __restrict__ ws1, const float* __restrict__ wd1,
    float* __restrict__ ssrc, float* __restrict__ sdst, int total) {
  __shared__ int sums[1024];
  if (blockIdx.x == 0) {
    int t = threadIdx.x;
    int per = (n + 1023) >> 10;
    int start = t * per; if (start > n) start = n;
    int end = start + per; if (end > n) end = n;
    int local = 0;
    for (int i = start; i < end; ++i) local += counts[i];
    sums[t] = local;
    __syncthreads();
    for (int off = 1; off < 1024; off <<= 1) {
      int add = (t >= off) ? sums[t - off] : 0;
      __syncthreads();
      sums[t] += add;
      __syncthreads();
    }
    int run = (t == 0) ? 0 : sums[t - 1];
    for (int i = start; i < end; ++i) {
      offsets[i] = run; cursor[i] = run; run += counts[i];
    }
    if (t == 1023) offsets[n] = run;
    return;
  }
  int idx = (blockIdx.x - 1) * 1024 + threadIdx.x;
  if (idx >= total) return;
  int nn = idx >> 3, h = idx & 7;
  float4 xv = *(const float4*)&x[nn * 4];
  float4 a = *(const float4*)&ws1[h * 4];
  float4 b = *(const float4*)&wd1[h * 4];
  ssrc[idx] = xv.x * a.x + xv.y * a.y + xv.z * a.z + xv.w * a.w;
  sdst[idx] = xv.x * b.x + xv.y * b.y + xv.z * b.z + xv.w * b.w;
}

__global__ void scatter_kernel(const int* __restrict__ ei, int E, int ET,
                               int* __restrict__ cursor, int* __restrict__ srcs) {
  int e = blockIdx.x * THREADS + threadIdx.x;
  if (e >= ET) return;
  int s = (e < E) ? ei[e] : (e - E);
  int d = (e < E) ? ei[E + e] : (e - E);
  int pos = atomicAdd(&cursor[d], 1);
  srcs[pos] = s;
}

// ---------------- fused attention + aggregation (P16), wave per node ----------------
// batch-8 gather + f32x2 packed accumulate (v_pk_fma_f32; identical rounding).

__global__ __launch_bounds__(256) void attnagg_p(const __half* __restrict__ P16,
                                                 const int* __restrict__ srcs,
                                                 const int* __restrict__ offsets,
                                                 const float* __restrict__ ssrc,
                                                 const float* __restrict__ sdst,
                                                 __half* __restrict__ Y16, int NP) {
  __shared__ float lal[4][CAP][8];
  __shared__ int ls[4][CAP];
  __shared__ float szinv[4][8];
  int w = threadIdx.x >> 6, lane = threadIdx.x & 63;
  int n = blockIdx.x * 4 + w;
  int start = offsets[n], deg = offsets[n + 1] - start;
  int head = lane & 7, es = lane >> 3;
  float sd = sdst[n * 8 + head];
  int c2 = lane * 2;
  const __half* pbase = P16 + c2;
  f32x2 acc2[8] = {};
  float s = 0.f;
  for (int cc = 0; cc < deg; cc += CAP) {
    int cm = min(CAP, deg - cc);
    for (int i = es; i < cm; i += 8) {
      int sp = srcs[start + cc + i];
      float v = ssrc[sp * 8 + head] + sd;
      v = (v > 0.f) ? v : 0.2f * v;
      float e = __expf(v);
      lal[w][i][head] = e;
      if (head == 0) ls[w][i] = sp;
      s += e;
    }
    int i = 0;
    for (; i + 8 <= cm; i += 8) {
      f32x2 pp[8];
#pragma unroll
      for (int u = 0; u < 8; ++u) {
        int sp = ls[w][i + u];
        float2 f = __half22float2(*(const __half2*)&pbase[(size_t)sp * 128]);
        pp[u].x = f.x; pp[u].y = f.y;
      }
#pragma unroll
      for (int u = 0; u < 8; ++u) {
        float4 a00 = *(float4*)&lal[w][i + u][0];
        float4 a01 = *(float4*)&lal[w][i + u][4];
        float a0[8] = {a00.x, a00.y, a00.z, a00.w, a01.x, a01.y, a01.z, a01.w};
#pragma unroll
        for (int h = 0; h < 8; ++h) acc2[h] += a0[h] * pp[u];
      }
    }
    for (; i < cm; ++i) {
      int sp0 = ls[w][i];
      float2 f = __half22float2(*(const __half2*)&pbase[(size_t)sp0 * 128]);
      f32x2 p0; p0.x = f.x; p0.y = f.y;
      float4 a00 = *(float4*)&lal[w][i][0];
      float4 a01 = *(float4*)&lal[w][i][4];
      float a0[8] = {a00.x, a00.y, a00.z, a00.w, a01.x, a01.y, a01.z, a01.w};
#pragma unroll
      for (int h = 0; h < 8; ++h) acc2[h] += a0[h] * p0;
    }
  }
#pragma unroll
  for (int mask = 8; mask <= 32; mask <<= 1)
    s += __shfl_xor(s, mask);
  if (es == 0) szinv[w][head] = 1.f / s;
#pragma unroll
  for (int h = 0; h < 8; ++h) {
    float zi = szinv[w][h];
    *(__half2*)&Y16[((size_t)h * NP + n) * 128 + c2] =
        __floats2half2_rn(acc2[h].x * zi, acc2[h].y * zi);
  }
}

// ---------------- fused attention + aggregation (layer 1, raw x) ----------------

__global__ __launch_bounds__(256) void attnagg_x(const float* __restrict__ x,
                                                 const int* __restrict__ srcs,
                                                 const int* __restrict__ offsets,
                                                 const float* __restrict__ ssrc,
                                                 const float* __restrict__ sdst,
                                                 float* __restrict__ Y1, int NP) {
  __shared__ float lal[4][CAP][8];
  __shared__ int ls[4][CAP];
  __shared__ float szinv[4][8];
  int w = threadIdx.x >> 6, lane = threadIdx.x & 63;
  int n = blockIdx.x * 4 + w;
  int start = offsets[n], deg = offsets[n + 1] - start;
  int head = lane & 7, es = lane >> 3;
  float sd = sdst[n * 8 + head];
  int eo = lane >> 5, hb = (lane >> 2) & 7, ch = lane & 3;
  float acc = 0.f;
  float s = 0.f;
  for (int cc = 0; cc < deg; cc += CAP) {
    int cm = min(CAP, deg - cc);
    for (int i = es; i < cm; i += 8) {
      int sp = srcs[start + cc + i];
      float v = ssrc[sp * 8 + head] + sd;
      v = (v > 0.f) ? v : 0.2f * v;
      float e = __expf(v);
      lal[w][i][head] = e;
      if (head == 0) ls[w][i] = sp;
      s += e;
    }
    int i = eo;
    for (; i + 6 < cm; i += 8) {
      float xv[4]; float av[4];
#pragma unroll
      for (int u = 0; u < 4; ++u) {
        int sp = ls[w][i + 2 * u];
        xv[u] = x[sp * 4 + ch];
      }
#pragma unroll
      for (int u = 0; u < 4; ++u) av[u] = lal[w][i + 2 * u][hb];
#pragma unroll
      for (int u = 0; u < 4; ++u) acc += av[u] * xv[u];
    }
    for (; i < cm; i += 2) {
      int sp = ls[w][i];
      acc += lal[w][i][hb] * x[sp * 4 + ch];
    }
  }
#pragma unroll
  for (int mask = 8; mask <= 32; mask <<= 1)
    s += __shfl_xor(s, mask);
  if (es == 0) szinv[w][head] = 1.f / s;
  acc += __shfl_xor(acc, 32);
  if (lane < 32) {
    float zi = szinv[w][hb];
    Y1[((size_t)hb * NP + n) * 4 + ch] = acc * zi;
  }
}

// ---------------- fused tail (layers 2/3): 32 rows, VGPR<=128, 16-slot ring ----------------

template <typename OutT, bool SC>
__global__ __launch_bounds__(512, 4) void tail_mfma(const __half* __restrict__ Y16,
                                                    const __half* __restrict__ WtA,
                                                    const float* __restrict__ biasA,
                                                    const __half* __restrict__ WtP,
                                                    const float* __restrict__ biasP,
                                                    OutT* __restrict__ out, int N, int NP,
                                                    const float* __restrict__ wsn,
                                                    const float* __restrict__ wdn,
                                                    float* __restrict__ ssrc,
                                                    float* __restrict__ sdst) {
  __shared__ __half Gt[32][1032];
  __shared__ __half Pl[32][136];
  int w = threadIdx.x >> 6, lane = threadIdx.x & 63;
  int r0 = blockIdx.x * 32;
  int m = lane & 15, quad = lane >> 4;
  // stage 1: G = gelu(Y @ WtA + biasA); WtA swizzled; double-buffered tiles
  {
    int h = w;
    const __half* py0 = Y16 + ((size_t)h * NP + r0 + m) * 128 + quad * 8;
    const __half* py1 = py0 + (size_t)16 * 128;
    f16x8 bf0[4], bf1[4];
#pragma unroll
    for (int kk = 0; kk < 4; ++kk) {
      bf0[kk] = *(const f16x8*)(py0 + kk * 32);
      bf1[kk] = *(const f16x8*)(py1 + kk * 32);
    }
    const __half* wbase = WtA + (size_t)h * 8 * 2048 + lane * 8;
    f16x8 aA[4], aB[4];
#pragma unroll
    for (int kk = 0; kk < 4; ++kk) aA[kk] = *(const f16x8*)(wbase + kk * 512);
#pragma unroll
    for (int tile = 0; tile < 8; ++tile) {
      if (tile < 7) {
        const __half* pn = wbase + (size_t)(tile + 1) * 2048;
        if ((tile & 1) == 0) {
#pragma unroll
          for (int kk = 0; kk < 4; ++kk) aB[kk] = *(const f16x8*)(pn + kk * 512);
        } else {
#pragma unroll
          for (int kk = 0; kk < 4; ++kk) aA[kk] = *(const f16x8*)(pn + kk * 512);
        }
      }
      int gc = w * 128 + tile * 16;
      f32x4 acc0 = {0.f, 0.f, 0.f, 0.f}, acc1 = {0.f, 0.f, 0.f, 0.f};
#pragma unroll
      for (int kk = 0; kk < 4; ++kk) {
        f16x8 av = ((tile & 1) == 0) ? aA[kk] : aB[kk];
        acc0 = __builtin_amdgcn_mfma_f32_16x16x32_f16(av, bf0[kk], acc0, 0, 0, 0);
        acc1 = __builtin_amdgcn_mfma_f32_16x16x32_f16(av, bf1[kk], acc1, 0, 0, 0);
      }
      float4 b4 = *(const float4*)&biasA[gc + quad * 4];
      Half4 p0, p1;
      p0.a = __floats2half2_rn(gelu_exact(acc0[0] + b4.x), gelu_exact(acc0[1] + b4.y));
      p0.b = __floats2half2_rn(gelu_exact(acc0[2] + b4.z), gelu_exact(acc0[3] + b4.w));
      p1.a = __floats2half2_rn(gelu_exact(acc1[0] + b4.x), gelu_exact(acc1[1] + b4.y));
      p1.b = __floats2half2_rn(gelu_exact(acc1[2] + b4.z), gelu_exact(acc1[3] + b4.w));
      *(Half4*)&Gt[m][gc + quad * 4] = p0;
      *(Half4*)&Gt[16 + m][gc + quad * 4] = p1;
    }
  }
  __syncthreads();
  // stage 2: 16-slot register ring
  {
    int c0 = w * 16;
    const __half* pa = WtP + (size_t)w * 16384 + lane * 8;
    f16x8 ring[16];
#pragma unroll
    for (int u = 0; u < 16; ++u) ring[u] = *(const f16x8*)(pa + u * 512);
    f32x4 acc0 = {0.f, 0.f, 0.f, 0.f}, acc1 = {0.f, 0.f, 0.f, 0.f};
#pragma unroll
    for (int u = 0; u < 32; ++u) {
      int k = u * 32;
      f16x8 av = ring[u & 15];
      f16x8 b0 = *(const f16x8*)&Gt[m][quad * 8 + k];
      f16x8 b1 = *(const f16x8*)&Gt[16 + m][quad * 8 + k];
      acc0 = __builtin_amdgcn_mfma_f32_16x16x32_f16(av, b0, acc0, 0, 0, 0);
      acc1 = __builtin_amdgcn_mfma_f32_16x16x32_f16(av, b1, acc1, 0, 0, 0);
      if (u < 16) ring[u & 15] = *(const f16x8*)(pa + (u + 16) * 512);
    }
    float4 b4 = *(const float4*)&biasP[c0 + quad * 4];
    int row0 = r0 + m, row1 = r0 + 16 + m;
    if constexpr (__is_same(OutT, __half)) {
      Half4 p, q;
      p.a = __floats2half2_rn(acc0[0] + b4.x, acc0[1] + b4.y);
      p.b = __floats2half2_rn(acc0[2] + b4.z, acc0[3] + b4.w);
      q.a = __floats2half2_rn(acc1[0] + b4.x, acc1[1] + b4.y);
      q.b = __floats2half2_rn(acc1[2] + b4.z, acc1[3] + b4.w);
      if constexpr (SC) {
        *(Half4*)&Pl[m][c0 + quad * 4] = p;
        *(Half4*)&Pl[16 + m][c0 + quad * 4] = q;
      }
      if (row0 < N) *(Half4*)&out[(size_t)row0 * 128 + c0 + quad * 4] = p;
      if (row1 < N) *(Half4*)&out[(size_t)row1 * 128 + c0 + quad * 4] = q;
    } else {
      if (row0 < N)
        *(float4*)&out[(size_t)row0 * 128 + c0 + quad * 4] =
            make_float4(acc0[0] + b4.x, acc0[1] + b4.y, acc0[2] + b4.z, acc0[3] + b4.w);
      if (row1 < N)
        *(float4*)&out[(size_t)row1 * 128 + c0 + quad * 4] =
            make_float4(acc1[0] + b4.x, acc1[1] + b4.y, acc1[2] + b4.z, acc1[3] + b4.w);
    }
  }
  if constexpr (SC) {
    __syncthreads();
    int head = lane & 7, es = lane >> 3;
    const float* wsp = wsn + head * 128 + es * 16;
    const float* wdp = wdn + head * 128 + es * 16;
    float wsr[16], wdr[16];
#pragma unroll
    for (int j = 0; j < 16; ++j) { wsr[j] = wsp[j]; wdr[j] = wdp[j]; }
#pragma unroll
    for (int r = 0; r < 4; ++r) {
      int row = w * 4 + r;
      f16x8 p0 = *(const f16x8*)&Pl[row][es * 16];
      f16x8 p1 = *(const f16x8*)&Pl[row][es * 16 + 8];
      float s1 = 0.f, s2 = 0.f;
#pragma unroll
      for (int j = 0; j < 8; ++j) {
        float v = (float)p0[j];
        s1 += v * wsr[j]; s2 += v * wdr[j];
      }
#pragma unroll
      for (int j = 0; j < 8; ++j) {
        float v = (float)p1[j];
        s1 += v * wsr[8 + j]; s2 += v * wdr[8 + j];
      }
#pragma unroll
      for (int mask = 8; mask <= 32; mask <<= 1) {
        s1 += __shfl_xor(s1, mask);
        s2 += __shfl_xor(s2, mask);
      }
      int nn = r0 + row;
      if (es == 0 && nn < N) { ssrc[nn * 8 + head] = s1; sdst[nn * 8 + head] = s2; }
    }
  }
}

// ---------------- fused tail (layer 1): 32 rows, VGPR<=128, 16-slot ring ----------------

template <typename OutT, bool SC>
__global__ __launch_bounds__(512, 4) void tail1_kernel(const float* __restrict__ Y1,
                                                       const float* __restrict__ w,
                                                       const float* __restrict__ biasA,
                                                       const __half* __restrict__ WtP,
                                                       const float* __restrict__ biasP,
                                                       OutT* __restrict__ out, int N, int NP,
                                                       const float* __restrict__ wsn,
                                                       const float* __restrict__ wdn,
                                                       float* __restrict__ ssrc,
                                                       float* __restrict__ sdst) {
  __shared__ __half Gt[32][1032];
  __shared__ __half Pl[32][136];
  int t = threadIdx.x;
  int r0 = blockIdx.x * 32;
  {
    int c0 = (t & 255) * 4;
    int h = c0 >> 7;
    float4 wa = *(const float4*)&w[c0];
    float4 wb = *(const float4*)&w[1024 + c0];
    float4 wc = *(const float4*)&w[2048 + c0];
    float4 wd = *(const float4*)&w[3072 + c0];
    float4 b4 = *(const float4*)&biasA[c0];
#pragma unroll 4
    for (int r = t >> 8; r < 32; r += 2) {
      float4 yv = *(const float4*)&Y1[((size_t)h * NP + r0 + r) * 4];
      float o0 = gelu_exact(yv.x * wa.x + yv.y * wb.x + yv.z * wc.x + yv.w * wd.x + b4.x);
      float o1 = gelu_exact(yv.x * wa.y + yv.y * wb.y + yv.z * wc.y + yv.w * wd.y + b4.y);
      float o2 = gelu_exact(yv.x * wa.z + yv.y * wb.z + yv.z * wc.z + yv.w * wd.z + b4.z);
      float o3 = gelu_exact(yv.x * wa.w + yv.y * wb.w + yv.z * wc.w + yv.w * wd.w + b4.w);
      Half4 p;
      p.a = __floats2half2_rn(o0, o1);
      p.b = __floats2half2_rn(o2, o3);
      *(Half4*)&Gt[r][c0] = p;
    }
  }
  __syncthreads();
  int wv = t >> 6, lane = t & 63;
  int m = lane & 15, quad = lane >> 4;
  {
    int c0 = wv * 16;
    const __half* pa = WtP + (size_t)wv * 16384 + lane * 8;
    f16x8 ring[16];
#pragma unroll
    for (int u = 0; u < 16; ++u) ring[u] = *(const f16x8*)(pa + u * 512);
    f32x4 acc0 = {0.f, 0.f, 0.f, 0.f}, acc1 = {0.f, 0.f, 0.f, 0.f};
#pragma unroll
    for (int u = 0; u < 32; ++u) {
      int k = u * 32;
      f16x8 av = ring[u & 15];
      f16x8 b0 = *(const f16x8*)&Gt[m][quad * 8 + k];
      f16x8 b1 = *(const f16x8*)&Gt[16 + m][quad * 8 + k];
      acc0 = __builtin_amdgcn_mfma_f32_16x16x32_f16(av, b0, acc0, 0, 0, 0);
      acc1 = __builtin_amdgcn_mfma_f32_16x16x32_f16(av, b1, acc1, 0, 0, 0);
      if (u < 16) ring[u & 15] = *(const f16x8*)(pa + (u + 16) * 512);
    }
    float4 b4 = *(const float4*)&biasP[c0 + quad * 4];
    int row0 = r0 + m, row1 = r0 + 16 + m;
    if constexpr (__is_same(OutT, __half)) {
      Half4 p, q;
      p.a = __floats2half2_rn(acc0[0] + b4.x, acc0[1] + b4.y);
      p.b = __floats2half2_rn(acc0[2] + b4.z, acc0[3] + b4.w);
      q.a = __floats2half2_rn(acc1[0] + b4.x, acc1[1] + b4.y);
      q.b = __floats2half2_rn(acc1[2] + b4.z, acc1[3] + b4.w);
      if constexpr (SC) {
        *(Half4*)&Pl[m][c0 + quad * 4] = p;
        *(Half4*)&Pl[16 + m][c0 + quad * 4] = q;
      }
      if (row0 < N) *(Half4*)&out[(size_t)row0 * 128 + c0 + quad * 4] = p;
      if (row1 < N) *(Half4*)&out[(size_t)row1 * 128 + c0 + quad * 4] = q;
    } else {
      if (row0 < N)
        *(float4*)&out[(size_t)row0 * 128 + c0 + quad * 4] =
            make_float4(acc0[0] + b4.x, acc0[1] + b4.y, acc0[2] + b4.z, acc0[3] + b4.w);
      if (row1 < N)
        *(float4*)&out[(size_t)row1 * 128 + c0 + quad * 4] =
            make_float4(acc1[0] + b4.x, acc1[1] + b4.y, acc1[2] + b4.z, acc1[3] + b4.w);
    }
  }
  if constexpr (SC) {
    __syncthreads();
    int head = lane & 7, es = lane >> 3;
    const float* wsp = wsn + head * 128 + es * 16;
    const float* wdp = wdn + head * 128 + es * 16;
    float wsr[16], wdr[16];
#pragma unroll
    for (int j = 0; j < 16; ++j) { wsr[j] = wsp[j]; wdr[j] = wdp[j]; }
#pragma unroll
    for (int r = 0; r < 4; ++r) {
      int row = wv * 4 + r;
      f16x8 p0 = *(const f16x8*)&Pl[row][es * 16];
      f16x8 p1 = *(const f16x8*)&Pl[row][es * 16 + 8];
      float s1 = 0.f, s2 = 0.f;
#pragma unroll
      for (int j = 0; j < 8; ++j) {
        float v = (float)p0[j];
        s1 += v * wsr[j]; s2 += v * wdr[j];
      }
#pragma unroll
      for (int j = 0; j < 8; ++j) {
        float v = (float)p1[j];
        s1 += v * wsr[8 + j]; s2 += v * wdr[8 + j];
      }
#pragma unroll
      for (int mask = 8; mask <= 32; mask <<= 1) {
        s1 += __shfl_xor(s1, mask);
        s2 += __shfl_xor(s2, mask);
      }
      int nn = r0 + row;
      if (es == 0 && nn < N) { ssrc[nn * 8 + head] = s1; sdst[nn * 8 + head] = s2; }
    }
  }
}

// ---------------- orchestration ----------------

extern "C" void kernel_launch(void* const* d_in, const int* in_sizes, int n_in,
                              void* d_out, int out_size, void* d_ws, size_t ws_size,
                              hipStream_t stream) {
  const float* x   = (const float*)d_in[0];
  const int*   ei  = (const int*)d_in[1];
  const float* w1  = (const float*)d_in[2];
  const float* as1 = (const float*)d_in[3];
  const float* ad1 = (const float*)d_in[4];
  const float* b1  = (const float*)d_in[5];
  const float* w2  = (const float*)d_in[6];
  const float* as2 = (const float*)d_in[7];
  const float* ad2 = (const float*)d_in[8];
  const float* b2  = (const float*)d_in[9];
  const float* w3  = (const float*)d_in[10];
  const float* as3 = (const float*)d_in[11];
  const float* ad3 = (const float*)d_in[12];
  const float* b3  = (const float*)d_in[13];
  const float* rw1 = (const float*)d_in[14];
  const float* rb1 = (const float*)d_in[15];
  const float* rw2 = (const float*)d_in[16];
  const float* rb2 = (const float*)d_in[17];
  const float* lw  = (const float*)d_in[18];
  const float* lb  = (const float*)d_in[19];

  int N = in_sizes[0] / 4;
  int E = in_sizes[1] / 2;
  int ET = E + N;
  int nRow32 = (N + 31) / 32;
  int NP = nRow32 * 32;          // padded rows (10016)
  (void)ws_size;

  char* wsb = (char*)d_ws;
  size_t off = 0;
  auto alloc = [&](size_t bytes) -> void* {
    void* p = wsb + off;
    off += (bytes + 255) & ~(size_t)255;
    return p;
  };
  __half* P16  = (__half*)alloc((size_t)N * 128 * 2);
  __half* Y16  = (__half*)alloc((size_t)8 * NP * 128 * 2);
  float*  Y1   = (float*)alloc((size_t)8 * NP * 4 * 4);
  __half* wt2  = (__half*)alloc((size_t)1024 * 128 * 2);
  __half* wt3  = (__half*)alloc((size_t)1024 * 128 * 2);
  __half* rwt1 = (__half*)alloc((size_t)128 * 1024 * 2);
  __half* rwt2 = (__half*)alloc((size_t)128 * 1024 * 2);
  __half* lwt  = (__half*)alloc((size_t)128 * 1024 * 2);
  float* ws1 = (float*)alloc(8 * 4 * 4);
  float* wd1 = (float*)alloc(8 * 4 * 4);
  float* ws2 = (float*)alloc(8 * 128 * 4);
  float* wd2 = (float*)alloc(8 * 128 * 4);
  float* ws3 = (float*)alloc(8 * 128 * 4);
  float* wd3 = (float*)alloc(8 * 128 * 4);
  float* ssrc   = (float*)alloc((size_t)N * 8 * 4);
  float* sdst   = (float*)alloc((size_t)N * 8 * 4);
  int* counts  = (int*)alloc((size_t)N * 4);
  int* offsets = (int*)alloc((size_t)(N + 1) * 4);
  int* cursor  = (int*)alloc((size_t)N * 4);
  int* srcs    = (int*)alloc((size_t)ET * 4);

  dim3 blk(THREADS);
  dim3 blk512(512);
  int nHist = (ET + THREADS - 1) / THREADS;

  hipMemsetAsync(counts, 0, (size_t)N * 4, stream);

  prep_kernel<<<dim3(nHist + 640 + 24), blk, 0, stream>>>(
      ei, E, ET, counts,
      w2, w3, rw1, rw2, lw, wt2, wt3, rwt1, rwt2, lwt,
      w1, as1, ad1, as2, ad2, as3, ad3,
      ws1, wd1, ws2, wd2, ws3, wd3, nHist);

  int total1 = N * 8;
  int nSc = (total1 + 1023) / 1024;
  scan_scores_kernel<<<dim3(1 + nSc), dim3(1024), 0, stream>>>(
      counts, offsets, cursor, N, x, ws1, wd1, ssrc, sdst, total1);

  scatter_kernel<<<dim3(nHist), blk, 0, stream>>>(ei, E, ET, cursor, srcs);

  dim3 gNode4(N / 4);
  dim3 gRow32(nRow32);

  // ---- layer 1 ----
  attnagg_x<<<gNode4, blk, 0, stream>>>(x, srcs, offsets, ssrc, sdst, Y1, NP);
  tail1_kernel<__half, true><<<gRow32, blk512, 0, stream>>>(
      Y1, w1, b1, rwt1, rb1, P16, N, NP, ws2, wd2, ssrc, sdst);

  // ---- layer 2 ----
  attnagg_p<<<gNode4, blk, 0, stream>>>(P16, srcs, offsets, ssrc, sdst, Y16, NP);
  tail_mfma<__half, true><<<gRow32, blk512, 0, stream>>>(
      Y16, wt2, b2, rwt2, rb2, P16, N, NP, ws3, wd3, ssrc, sdst);

  // ---- layer 3 ----
  attnagg_p<<<gNode4, blk, 0, stream>>>(P16, srcs, offsets, ssrc, sdst, Y16, NP);
  tail_mfma<float, false><<<gRow32, blk512, 0, stream>>>(
      Y16, wt3, b3, lwt, lb, (float*)d_out, N, NP, nullptr, nullptr, nullptr, nullptr);
}